// Round 4
// baseline (3138.970 us; speedup 1.0000x reference)
//
#include <hip/hip_runtime.h>
#include <stdint.h>

typedef signed char i8;

#define S_IN  0.05f
#define S_Z   0.02f
#define S_U   0.01f
#define S_DTLN 0.02f
#define S_B   0.02f
#define S_C   0.02f
#define S_DT  0.01f
#define S_Y   0.01f

__device__ __forceinline__ int dot4(int a, int b, int c) {
    return __builtin_amdgcn_sdot4(a, b, c, false);
}

// qa(): round-half-even (matches jnp.round), clip to [-128,127]
__device__ __forceinline__ float q8f(float x, float s) {
    float r = rintf(x / s);
    return fmaxf(-128.0f, fminf(127.0f, r));
}
__device__ __forceinline__ int q8i(float x, float s) { return (int)q8f(x, s); }

__device__ __forceinline__ float softplus_f(float x) {
    // jnp.logaddexp(x,0) = max(x,0) + log1p(exp(-|x|))
    return __fadd_rn(fmaxf(x, 0.0f), log1pf(expf(-fabsf(x))));
}

// ---------------- max|w| reduction ----------------
__global__ __launch_bounds__(256)
void k_maxabs(const float* __restrict__ w, long long n, unsigned* __restrict__ out) {
    unsigned m = 0;
    long long stride = (long long)gridDim.x * 256;
    for (long long i = (long long)blockIdx.x * 256 + threadIdx.x; i < n; i += stride)
        m = max(m, __float_as_uint(fabsf(w[i])));
    #pragma unroll
    for (int off = 32; off; off >>= 1) {
        unsigned o = (unsigned)__shfl_xor((int)m, off);
        m = max(m, o);
    }
    __shared__ unsigned sm[4];
    if ((threadIdx.x & 63) == 0) sm[threadIdx.x >> 6] = m;
    __syncthreads();
    if (threadIdx.x == 0) {
        unsigned r = max(max(sm[0], sm[1]), max(sm[2], sm[3]));
        atomicMax(out, r);
    }
}

// ---------------- weight quant: wq = clip(round(w/(max/127))) ----------------
__global__ __launch_bounds__(256)
void k_quant_w(const float* __restrict__ w, long long n,
               const unsigned* __restrict__ maxbits, i8* __restrict__ o) {
    long long i = ((long long)blockIdx.x * 256 + threadIdx.x) * 4;
    if (i >= n) return;
    float s = __uint_as_float(*maxbits) / 127.0f;
    float4 v = *(const float4*)(w + i);
    unsigned pk = ((unsigned)(q8i(v.x, s) & 255))
                | ((unsigned)(q8i(v.y, s) & 255) << 8)
                | ((unsigned)(q8i(v.z, s) & 255) << 16)
                | ((unsigned)(q8i(v.w, s) & 255) << 24);
    *(unsigned*)(o + i) = pk;
}

// ---------------- activation quant (fixed scale) ----------------
__global__ __launch_bounds__(256)
void k_quant_x(const float* __restrict__ x, long long n, float s, i8* __restrict__ o) {
    long long i = ((long long)blockIdx.x * 256 + threadIdx.x) * 4;
    if (i >= n) return;
    float4 v = *(const float4*)(x + i);
    unsigned pk = ((unsigned)(q8i(v.x, s) & 255))
                | ((unsigned)(q8i(v.y, s) & 255) << 8)
                | ((unsigned)(q8i(v.z, s) & 255) << 16)
                | ((unsigned)(q8i(v.w, s) & 255) << 24);
    *(unsigned*)(o + i) = pk;
}

// ---------------- int8 GEMM: C[M,N] = A[M,K] * B[N,K]^T, 4 epilogues ----------------
// EPI 0: in_proj  -> int8, transposed split to hs[b,j,s] / gate[b,j-4096,s]
// EPI 1: x_proj   -> f32 ssm_p[m,160]
// EPI 2: dt_proj  -> int8 dt8[b,j,s] (transposed)
// EPI 3: out_proj -> f32 out[m,N]
template<int EPI>
__global__ __launch_bounds__(256)
void k_gemm(const i8* __restrict__ A, const i8* __restrict__ Bw,
            int M, int N, int K,
            const unsigned* __restrict__ wmaxbits,
            void* __restrict__ out0, void* __restrict__ out1) {
    __shared__ int As[64][17];
    __shared__ int Bs[64][17];
    const int tid = threadIdx.x;
    const int m0 = blockIdx.y << 6;
    const int n0 = blockIdx.x << 6;
    const int tx = tid & 15;       // N dir
    const int ty = tid >> 4;       // M dir
    const int ldr = tid >> 2;      // load row 0..63
    const int ldw = (tid & 3) << 2;// load word 0,4,8,12
    int acc[4][4] = {};
    for (int k0 = 0; k0 < K; k0 += 64) {
        int4 av = *(const int4*)(A + (size_t)(m0 + ldr) * K + k0 + (ldw << 2));
        int4 bv = make_int4(0, 0, 0, 0);
        if (n0 + ldr < N)
            bv = *(const int4*)(Bw + (size_t)(n0 + ldr) * K + k0 + (ldw << 2));
        As[ldr][ldw + 0] = av.x; As[ldr][ldw + 1] = av.y;
        As[ldr][ldw + 2] = av.z; As[ldr][ldw + 3] = av.w;
        Bs[ldr][ldw + 0] = bv.x; Bs[ldr][ldw + 1] = bv.y;
        Bs[ldr][ldw + 2] = bv.z; Bs[ldr][ldw + 3] = bv.w;
        __syncthreads();
        #pragma unroll
        for (int kk = 0; kk < 16; kk++) {
            const int a0 = As[(ty << 2) + 0][kk];
            const int a1 = As[(ty << 2) + 1][kk];
            const int a2 = As[(ty << 2) + 2][kk];
            const int a3 = As[(ty << 2) + 3][kk];
            const int b0 = Bs[(tx << 2) + 0][kk];
            const int b1 = Bs[(tx << 2) + 1][kk];
            const int b2 = Bs[(tx << 2) + 2][kk];
            const int b3 = Bs[(tx << 2) + 3][kk];
            acc[0][0] = dot4(a0, b0, acc[0][0]); acc[0][1] = dot4(a0, b1, acc[0][1]);
            acc[0][2] = dot4(a0, b2, acc[0][2]); acc[0][3] = dot4(a0, b3, acc[0][3]);
            acc[1][0] = dot4(a1, b0, acc[1][0]); acc[1][1] = dot4(a1, b1, acc[1][1]);
            acc[1][2] = dot4(a1, b2, acc[1][2]); acc[1][3] = dot4(a1, b3, acc[1][3]);
            acc[2][0] = dot4(a2, b0, acc[2][0]); acc[2][1] = dot4(a2, b1, acc[2][1]);
            acc[2][2] = dot4(a2, b2, acc[2][2]); acc[2][3] = dot4(a2, b3, acc[2][3]);
            acc[3][0] = dot4(a3, b0, acc[3][0]); acc[3][1] = dot4(a3, b1, acc[3][1]);
            acc[3][2] = dot4(a3, b2, acc[3][2]); acc[3][3] = dot4(a3, b3, acc[3][3]);
        }
        __syncthreads();
    }
    const float wsc = __uint_as_float(*wmaxbits) / 127.0f;
    if constexpr (EPI == 0) {
        const float sc = S_IN * wsc;
        const int b = m0 >> 11;
        const int s0 = (m0 & 2047) + (ty << 2);
        #pragma unroll
        for (int c = 0; c < 4; c++) {
            const int j = n0 + (tx << 2) + c;
            unsigned pk = 0;
            #pragma unroll
            for (int r = 0; r < 4; r++) {
                float v = (float)acc[r][c] * sc;
                pk |= ((unsigned)(q8i(v, S_Z) & 255)) << (8 * r);
            }
            i8* dst = (j < 4096) ? (i8*)out0 : (i8*)out1;
            const int jj = j & 4095;
            *(unsigned*)(dst + ((size_t)b * 4096 + jj) * 2048 + s0) = pk;
        }
    } else if constexpr (EPI == 1) {
        const float sc = S_U * wsc;
        float* O = (float*)out0;
        const int j0 = n0 + (tx << 2);
        #pragma unroll
        for (int r = 0; r < 4; r++) {
            const int m = m0 + (ty << 2) + r;
            if (j0 + 3 < N) {
                float4 v;
                v.x = (float)acc[r][0] * sc; v.y = (float)acc[r][1] * sc;
                v.z = (float)acc[r][2] * sc; v.w = (float)acc[r][3] * sc;
                *(float4*)(O + (size_t)m * N + j0) = v;
            } else {
                for (int c = 0; c < 4; c++)
                    if (j0 + c < N) O[(size_t)m * N + j0 + c] = (float)acc[r][c] * sc;
            }
        }
    } else if constexpr (EPI == 2) {
        const float sc = S_DTLN * wsc;
        const int b = m0 >> 11;
        const int s0 = (m0 & 2047) + (ty << 2);
        i8* dst = (i8*)out0;
        #pragma unroll
        for (int c = 0; c < 4; c++) {
            const int j = n0 + (tx << 2) + c;
            unsigned pk = 0;
            #pragma unroll
            for (int r = 0; r < 4; r++) {
                float v = (float)acc[r][c] * sc;
                pk |= ((unsigned)(q8i(v, S_DT) & 255)) << (8 * r);
            }
            *(unsigned*)(dst + ((size_t)b * 4096 + j) * 2048 + s0) = pk;
        }
    } else {
        const float sc = S_Y * wsc;
        float* O = (float*)out0;
        const int j0 = n0 + (tx << 2);
        #pragma unroll
        for (int r = 0; r < 4; r++) {
            const int m = m0 + (ty << 2) + r;
            float4 v;
            v.x = (float)acc[r][0] * sc; v.y = (float)acc[r][1] * sc;
            v.z = (float)acc[r][2] * sc; v.w = (float)acc[r][3] * sc;
            *(float4*)(O + (size_t)m * N + j0) = v;
        }
    }
}

// ---------------- depthwise causal conv(K=4) + silu + quant ----------------
// in: hs_q[b,d,s] int8; out: u_q[b,d,s] int8 and u_qT[b,s,d] int8
__global__ __launch_bounds__(256)
void k_conv(const i8* __restrict__ hsq, const i8* __restrict__ cwq,
            const float* __restrict__ conv_b, const unsigned* __restrict__ cmaxbits,
            i8* __restrict__ uq, i8* __restrict__ uqT) {
    __shared__ char lt[64][68];
    const int tid = threadIdx.x;
    const int b = blockIdx.z;
    const int d0 = blockIdx.y << 6;
    const int s0 = blockIdx.x << 6;
    const int dl = tid >> 2;
    const int sg = tid & 3;
    const int d = d0 + dl;
    const int sbase = s0 + (sg << 4);
    const i8* xp = hsq + ((size_t)b * 4096 + d) * 2048;
    int v[19];
    #pragma unroll
    for (int i = 0; i < 19; i++) {
        int s = sbase - 3 + i;
        v[i] = (s >= 0) ? (int)xp[s] : 0;
    }
    const unsigned cw = *(const unsigned*)(cwq + (size_t)d * 4);
    const int w0 = (int)(char)(cw & 255);
    const int w1 = (int)(char)((cw >> 8) & 255);
    const int w2 = (int)(char)((cw >> 16) & 255);
    const int w3 = (int)(char)((cw >> 24) & 255);
    const float cws = __uint_as_float(*cmaxbits) / 127.0f;
    const float sc = S_Z * cws;
    const float bias = conv_b[d];
    unsigned pk[4] = {0, 0, 0, 0};
    #pragma unroll
    for (int t = 0; t < 16; t++) {
        int acc = v[t] * w0 + v[t + 1] * w1 + v[t + 2] * w2 + v[t + 3] * w3;
        float f = __fadd_rn(__fmul_rn((float)acc, sc), bias);
        float sig = 1.0f / (1.0f + expf(-f));
        float sl = __fmul_rn(f, sig);           // silu
        int q = q8i(sl, S_U);
        pk[t >> 2] |= ((unsigned)(q & 255)) << ((t & 3) * 8);
        lt[(sg << 4) + t][dl] = (char)q;
    }
    *(int4*)(uq + ((size_t)b * 4096 + d) * 2048 + sbase) = make_int4(pk[0], pk[1], pk[2], pk[3]);
    __syncthreads();
    const int rr = tid >> 2;
    const int wg = tid & 3;
    const int* rp = (const int*)(&lt[rr][wg << 4]);
    int4 o; o.x = rp[0]; o.y = rp[1]; o.z = rp[2]; o.w = rp[3];
    *(int4*)(uqT + ((size_t)b * 2048 + s0 + rr) * 4096 + d0 + (wg << 4)) = o;
}

// ---------------- rmsnorm + quant for dt(128), B(16), C(16) ----------------
__global__ __launch_bounds__(64)
void k_rms(const float* __restrict__ p,
           const float* __restrict__ wdt, const float* __restrict__ wB, const float* __restrict__ wC,
           i8* __restrict__ dtq, i8* __restrict__ bq, i8* __restrict__ cq) {
    const int row = blockIdx.x;
    const int lane = threadIdx.x;
    const float* x = p + (size_t)row * 160;
    float a0 = x[lane], a1 = x[64 + lane];
    float bb = (lane < 16) ? x[128 + lane] : 0.0f;
    float cc = (lane < 16) ? x[144 + lane] : 0.0f;
    float sdt = __fadd_rn(__fmul_rn(a0, a0), __fmul_rn(a1, a1));
    float sB = __fmul_rn(bb, bb);
    float sC = __fmul_rn(cc, cc);
    #pragma unroll
    for (int off = 32; off; off >>= 1) {
        sdt = __fadd_rn(sdt, __shfl_xor(sdt, off));
        sB  = __fadd_rn(sB,  __shfl_xor(sB, off));
        sC  = __fadd_rn(sC,  __shfl_xor(sC, off));
    }
    float rdt = 1.0f / sqrtf(sdt / 128.0f + 1e-6f);
    float rB  = 1.0f / sqrtf(sB / 16.0f + 1e-6f);
    float rC  = 1.0f / sqrtf(sC / 16.0f + 1e-6f);
    dtq[(size_t)row * 128 + lane]      = (i8)q8i(__fmul_rn(wdt[lane],      __fmul_rn(a0, rdt)), S_DTLN);
    dtq[(size_t)row * 128 + 64 + lane] = (i8)q8i(__fmul_rn(wdt[64 + lane], __fmul_rn(a1, rdt)), S_DTLN);
    if (lane < 16) {
        bq[(size_t)row * 16 + lane] = (i8)q8i(__fmul_rn(wB[lane], __fmul_rn(bb, rB)), S_B);
        cq[(size_t)row * 16 + lane] = (i8)q8i(__fmul_rn(wC[lane], __fmul_rn(cc, rC)), S_C);
    }
}

// ---------------- selective scan: lane per (b,d,n), 16-lane reduce ----------------
__global__ __launch_bounds__(256)
void k_scan(const i8* __restrict__ dt8, const i8* __restrict__ uq, const i8* __restrict__ gq,
            const i8* __restrict__ Bq, const i8* __restrict__ Cq,
            const float* __restrict__ A_log, const float* __restrict__ dt_bias,
            const float* __restrict__ D_skip, i8* __restrict__ yq) {
    const int g = blockIdx.x * 256 + threadIdx.x;
    const int n = g & 15;
    const int bd = g >> 4;           // b*4096 + d
    const int d = bd & 4095;
    const int b = bd >> 12;
    const float Acoef = -expf(A_log[(size_t)d * 16 + n]);
    const float bias = dt_bias[d];
    const float Dd = D_skip[d];
    const i8* dtp = dt8 + (size_t)bd * 2048;
    const i8* up  = uq  + (size_t)bd * 2048;
    const i8* gp  = gq  + (size_t)bd * 2048;
    const i8* Bp  = Bq + (size_t)b * 2048 * 16 + n;
    const i8* Cp  = Cq + (size_t)b * 2048 * 16 + n;
    i8* yp = yq + (size_t)b * 2048 * 4096 + d;
    float h = 0.0f;
    for (int s = 0; s < 2048; s++) {
        float dtv = softplus_f(__fadd_rn(__fmul_rn((float)dtp[s], S_DT), bias));
        float uv = __fmul_rn((float)up[s], S_U);
        float dA = expf(__fmul_rn(dtv, Acoef));
        float Bv = __fmul_rn((float)Bp[(size_t)s * 16], S_B);
        float Cv = __fmul_rn((float)Cp[(size_t)s * 16], S_C);
        h = __fadd_rn(__fmul_rn(h, dA), __fmul_rn(__fmul_rn(dtv, uv), Bv));
        float y = __fmul_rn(h, Cv);
        y = __fadd_rn(y, __shfl_xor(y, 1));
        y = __fadd_rn(y, __shfl_xor(y, 2));
        y = __fadd_rn(y, __shfl_xor(y, 4));
        y = __fadd_rn(y, __shfl_xor(y, 8));
        if (n == 0) {
            float ys = __fadd_rn(y, __fmul_rn(uv, Dd));
            float gv = __fmul_rn((float)gp[s], S_Z);
            float sg = __fmul_rn(gv, 1.0f / (1.0f + expf(-gv)));
            float v = __fmul_rn(ys, sg);
            yp[(size_t)s * 4096] = (i8)q8i(v, S_Y);
        }
    }
}

extern "C" void kernel_launch(void* const* d_in, const int* in_sizes, int n_in,
                              void* d_out, int out_size, void* d_ws, size_t ws_size,
                              hipStream_t stream) {
    const float* hidden   = (const float*)d_in[0];   // (2,2048,2048) f32
    const float* in_proj  = (const float*)d_in[1];   // (8192,2048)
    const float* conv_w   = (const float*)d_in[2];   // (4096,4)
    const float* conv_b   = (const float*)d_in[3];   // (4096,)
    const float* x_proj   = (const float*)d_in[4];   // (160,4096)
    const float* dt_ln    = (const float*)d_in[5];
    const float* B_ln     = (const float*)d_in[6];
    const float* C_ln     = (const float*)d_in[7];
    const float* dt_proj  = (const float*)d_in[8];   // (4096,128)
    const float* dt_bias  = (const float*)d_in[9];
    const float* A_log    = (const float*)d_in[10];  // (4096,16)
    const float* D_skip   = (const float*)d_in[11];
    const float* out_proj = (const float*)d_in[12];  // (2048,4096)
    float* out = (float*)d_out;                      // (2,2048,2048) f32 = 33.55 MB

    // ---- workspace layout, 46.4 MB total, lifetime-packed ----
    char* ws = (char*)d_ws;
    unsigned* scales = (unsigned*)ws;                       // 256 B: [0..4] weight absmax bits
    i8* WQ   = (i8*)(ws + 256);                             // 16,777,216: in_proj q8 -> u_qT -> y_q
    i8* XQ   = (i8*)(ws + 256 + 16777216);                  //  8,388,608: x_q -> OWQ (out_proj q8)
    i8* HSQ  = (i8*)(ws + 256 + 25165824);                  // 16,777,216: hs_q -> dt8
    float* SSMP = (float*)(ws + 256 + 41943040);            //  2,621,440 B: ssm_p [4096][160] f32
    i8* DTQ  = (i8*)(ws + 256 + 44564480);                  //    524,288: dt_q [4096][128]
    i8* BQ   = (i8*)(ws + 256 + 45088768);                  //     65,536: B_q [2][2048][16]
    i8* CQ   = (i8*)(ws + 256 + 45154304);                  //     65,536: C_q
    i8* XWQ  = (i8*)(ws + 256 + 45219840);                  //    655,360: x_proj q8
    i8* DWQ  = (i8*)(ws + 256 + 45875200);                  //    524,288: dt_proj q8
    i8* CWQ  = (i8*)(ws + 256 + 46399488);                  //     16,384: conv q8
    // end: 46,416,128 bytes

    // d_out doubles as scratch for the two scan-only 16.7MB tensors
    // (exactly 2 x 16,777,216 = 33,554,432 = out_size*4); both are fully
    // rewritten every call and dead before GEMM4 writes d_out.
    i8* GQ = (i8*)d_out;                                    // gate_q [2][4096][2048]
    i8* UQ = (i8*)d_out + 16777216;                         // u_q    [2][4096][2048]
    i8* UQT = WQ;                                           // u_qT [2][2048][4096]
    i8* OWQ = XQ;                                           // out_proj q8 [2048][4096]
    i8* DT8 = HSQ;                                          // dt8 [2][4096][2048]
    i8* YQ  = WQ;                                           // y_q [2][2048][4096]

    hipMemsetAsync(scales, 0, 256, stream);

    k_maxabs<<<2048, 256, 0, stream>>>(in_proj, 16777216LL, scales + 0);
    k_maxabs<<<64,   256, 0, stream>>>(conv_w,  16384LL,    scales + 1);
    k_maxabs<<<512,  256, 0, stream>>>(x_proj,  655360LL,   scales + 2);
    k_maxabs<<<512,  256, 0, stream>>>(dt_proj, 524288LL,   scales + 3);
    k_maxabs<<<1024, 256, 0, stream>>>(out_proj, 8388608LL, scales + 4);

    k_quant_w<<<16384, 256, 0, stream>>>(in_proj, 16777216LL, scales + 0, WQ);
    k_quant_w<<<16,    256, 0, stream>>>(conv_w,  16384LL,    scales + 1, CWQ);
    k_quant_w<<<640,   256, 0, stream>>>(x_proj,  655360LL,   scales + 2, XWQ);
    k_quant_w<<<512,   256, 0, stream>>>(dt_proj, 524288LL,   scales + 3, DWQ);
    k_quant_x<<<8192,  256, 0, stream>>>(hidden,  8388608LL,  S_IN, XQ);

    // GEMM1: proj = x_q[4096x2048] @ in_proj^T -> hs_q(HSQ) / gate_q(GQ), int8 [b,d,s]
    dim3 g1(128, 64);
    k_gemm<0><<<g1, 256, 0, stream>>>(XQ, WQ, 4096, 8192, 2048, scales + 0, HSQ, GQ);

    // x_q dead -> quantize out_proj into XQ region
    k_quant_w<<<8192, 256, 0, stream>>>(out_proj, 8388608LL, scales + 4, OWQ);

    // conv + silu + quant: hs_q -> u_q(UQ,[b,d,s]) and u_qT(WQ region,[b,s,d]); WQ(in_proj q8) dead
    dim3 gc(32, 64, 2);
    k_conv<<<gc, 256, 0, stream>>>(HSQ, CWQ, conv_b, scales + 1, UQ, UQT);

    // GEMM2: ssm_p = u_qT[4096x4096] @ x_proj^T[4096x160] -> f32
    dim3 g2(3, 64);
    k_gemm<1><<<g2, 256, 0, stream>>>(UQT, XWQ, 4096, 160, 4096, scales + 2, SSMP, nullptr);

    k_rms<<<4096, 64, 0, stream>>>(SSMP, dt_ln, B_ln, C_ln, DTQ, BQ, CQ);

    // GEMM3: dt8 = dt_q[4096x128] @ dt_proj^T[128x4096] -> int8 [b,d,s] into HSQ (hs_q dead)
    dim3 g3(64, 64);
    k_gemm<2><<<g3, 256, 0, stream>>>(DTQ, DWQ, 4096, 4096, 128, scales + 3, DT8, nullptr);

    // scan: -> y_q [b,s,d] into WQ region (u_qT dead after GEMM2)
    k_scan<<<512, 256, 0, stream>>>(DT8, UQ, GQ, BQ, CQ, A_log, dt_bias, D_skip, YQ);

    // GEMM4: out = y_q[4096x4096] @ out_proj^T[4096x2048] -> f32 (overwrites GQ/UQ, both dead)
    dim3 g4(32, 64);
    k_gemm<3><<<g4, 256, 0, stream>>>(YQ, OWQ, 4096, 2048, 4096, scales + 4, out, nullptr);
}

// Round 5
// 2500.589 us; speedup vs baseline: 1.2553x; 1.2553x over previous
//
#include <hip/hip_runtime.h>
#include <stdint.h>

typedef signed char i8;

#define S_IN  0.05f
#define S_Z   0.02f
#define S_U   0.01f
#define S_DTLN 0.02f
#define S_B   0.02f
#define S_C   0.02f
#define S_DT  0.01f
#define S_Y   0.01f

__device__ __forceinline__ int dot4(int a, int b, int c) {
    return __builtin_amdgcn_sdot4(a, b, c, false);
}

// qa(): round-half-even (matches jnp.round), clip to [-128,127]
__device__ __forceinline__ float q8f(float x, float s) {
    float r = rintf(x / s);
    return fmaxf(-128.0f, fminf(127.0f, r));
}
__device__ __forceinline__ int q8i(float x, float s) { return (int)q8f(x, s); }

__device__ __forceinline__ float softplus_f(float x) {
    // jnp.logaddexp(x,0) = max(x,0) + log1p(exp(-|x|))
    return __fadd_rn(fmaxf(x, 0.0f), log1pf(expf(-fabsf(x))));
}

// ---------------- max|w| reduction ----------------
__global__ __launch_bounds__(256)
void k_maxabs(const float* __restrict__ w, long long n, unsigned* __restrict__ out) {
    unsigned m = 0;
    long long stride = (long long)gridDim.x * 256;
    for (long long i = (long long)blockIdx.x * 256 + threadIdx.x; i < n; i += stride)
        m = max(m, __float_as_uint(fabsf(w[i])));
    #pragma unroll
    for (int off = 32; off; off >>= 1) {
        unsigned o = (unsigned)__shfl_xor((int)m, off);
        m = max(m, o);
    }
    __shared__ unsigned sm[4];
    if ((threadIdx.x & 63) == 0) sm[threadIdx.x >> 6] = m;
    __syncthreads();
    if (threadIdx.x == 0) {
        unsigned r = max(max(sm[0], sm[1]), max(sm[2], sm[3]));
        atomicMax(out, r);
    }
}

// ---------------- weight quant: wq = clip(round(w/(max/127))) ----------------
__global__ __launch_bounds__(256)
void k_quant_w(const float* __restrict__ w, long long n,
               const unsigned* __restrict__ maxbits, i8* __restrict__ o) {
    long long i = ((long long)blockIdx.x * 256 + threadIdx.x) * 4;
    if (i >= n) return;
    float s = __uint_as_float(*maxbits) / 127.0f;
    float4 v = *(const float4*)(w + i);
    unsigned pk = ((unsigned)(q8i(v.x, s) & 255))
                | ((unsigned)(q8i(v.y, s) & 255) << 8)
                | ((unsigned)(q8i(v.z, s) & 255) << 16)
                | ((unsigned)(q8i(v.w, s) & 255) << 24);
    *(unsigned*)(o + i) = pk;
}

// ---------------- activation quant (fixed scale) ----------------
__global__ __launch_bounds__(256)
void k_quant_x(const float* __restrict__ x, long long n, float s, i8* __restrict__ o) {
    long long i = ((long long)blockIdx.x * 256 + threadIdx.x) * 4;
    if (i >= n) return;
    float4 v = *(const float4*)(x + i);
    unsigned pk = ((unsigned)(q8i(v.x, s) & 255))
                | ((unsigned)(q8i(v.y, s) & 255) << 8)
                | ((unsigned)(q8i(v.z, s) & 255) << 16)
                | ((unsigned)(q8i(v.w, s) & 255) << 24);
    *(unsigned*)(o + i) = pk;
}

// ---------------- int8 GEMM: C[M,N] = A[M,K] * B[N,K]^T, 4 epilogues ----------------
template<int EPI>
__global__ __launch_bounds__(256)
void k_gemm(const i8* __restrict__ A, const i8* __restrict__ Bw,
            int M, int N, int K,
            const unsigned* __restrict__ wmaxbits,
            void* __restrict__ out0, void* __restrict__ out1) {
    __shared__ int As[64][17];
    __shared__ int Bs[64][17];
    const int tid = threadIdx.x;
    const int m0 = blockIdx.y << 6;
    const int n0 = blockIdx.x << 6;
    const int tx = tid & 15;       // N dir
    const int ty = tid >> 4;       // M dir
    const int ldr = tid >> 2;      // load row 0..63
    const int ldw = (tid & 3) << 2;// load word 0,4,8,12
    int acc[4][4] = {};
    for (int k0 = 0; k0 < K; k0 += 64) {
        int4 av = *(const int4*)(A + (size_t)(m0 + ldr) * K + k0 + (ldw << 2));
        int4 bv = make_int4(0, 0, 0, 0);
        if (n0 + ldr < N)
            bv = *(const int4*)(Bw + (size_t)(n0 + ldr) * K + k0 + (ldw << 2));
        As[ldr][ldw + 0] = av.x; As[ldr][ldw + 1] = av.y;
        As[ldr][ldw + 2] = av.z; As[ldr][ldw + 3] = av.w;
        Bs[ldr][ldw + 0] = bv.x; Bs[ldr][ldw + 1] = bv.y;
        Bs[ldr][ldw + 2] = bv.z; Bs[ldr][ldw + 3] = bv.w;
        __syncthreads();
        #pragma unroll
        for (int kk = 0; kk < 16; kk++) {
            const int a0 = As[(ty << 2) + 0][kk];
            const int a1 = As[(ty << 2) + 1][kk];
            const int a2 = As[(ty << 2) + 2][kk];
            const int a3 = As[(ty << 2) + 3][kk];
            const int b0 = Bs[(tx << 2) + 0][kk];
            const int b1 = Bs[(tx << 2) + 1][kk];
            const int b2 = Bs[(tx << 2) + 2][kk];
            const int b3 = Bs[(tx << 2) + 3][kk];
            acc[0][0] = dot4(a0, b0, acc[0][0]); acc[0][1] = dot4(a0, b1, acc[0][1]);
            acc[0][2] = dot4(a0, b2, acc[0][2]); acc[0][3] = dot4(a0, b3, acc[0][3]);
            acc[1][0] = dot4(a1, b0, acc[1][0]); acc[1][1] = dot4(a1, b1, acc[1][1]);
            acc[1][2] = dot4(a1, b2, acc[1][2]); acc[1][3] = dot4(a1, b3, acc[1][3]);
            acc[2][0] = dot4(a2, b0, acc[2][0]); acc[2][1] = dot4(a2, b1, acc[2][1]);
            acc[2][2] = dot4(a2, b2, acc[2][2]); acc[2][3] = dot4(a2, b3, acc[2][3]);
            acc[3][0] = dot4(a3, b0, acc[3][0]); acc[3][1] = dot4(a3, b1, acc[3][1]);
            acc[3][2] = dot4(a3, b2, acc[3][2]); acc[3][3] = dot4(a3, b3, acc[3][3]);
        }
        __syncthreads();
    }
    const float wsc = __uint_as_float(*wmaxbits) / 127.0f;
    if constexpr (EPI == 0) {
        const float sc = S_IN * wsc;
        const int b = m0 >> 11;
        const int s0 = (m0 & 2047) + (ty << 2);
        #pragma unroll
        for (int c = 0; c < 4; c++) {
            const int j = n0 + (tx << 2) + c;
            unsigned pk = 0;
            #pragma unroll
            for (int r = 0; r < 4; r++) {
                float v = (float)acc[r][c] * sc;
                pk |= ((unsigned)(q8i(v, S_Z) & 255)) << (8 * r);
            }
            i8* dst = (j < 4096) ? (i8*)out0 : (i8*)out1;
            const int jj = j & 4095;
            *(unsigned*)(dst + ((size_t)b * 4096 + jj) * 2048 + s0) = pk;
        }
    } else if constexpr (EPI == 1) {
        const float sc = S_U * wsc;
        float* O = (float*)out0;
        const int j0 = n0 + (tx << 2);
        #pragma unroll
        for (int r = 0; r < 4; r++) {
            const int m = m0 + (ty << 2) + r;
            if (j0 + 3 < N) {
                float4 v;
                v.x = (float)acc[r][0] * sc; v.y = (float)acc[r][1] * sc;
                v.z = (float)acc[r][2] * sc; v.w = (float)acc[r][3] * sc;
                *(float4*)(O + (size_t)m * N + j0) = v;
            } else {
                for (int c = 0; c < 4; c++)
                    if (j0 + c < N) O[(size_t)m * N + j0 + c] = (float)acc[r][c] * sc;
            }
        }
    } else if constexpr (EPI == 2) {
        const float sc = S_DTLN * wsc;
        const int b = m0 >> 11;
        const int s0 = (m0 & 2047) + (ty << 2);
        i8* dst = (i8*)out0;
        #pragma unroll
        for (int c = 0; c < 4; c++) {
            const int j = n0 + (tx << 2) + c;
            unsigned pk = 0;
            #pragma unroll
            for (int r = 0; r < 4; r++) {
                float v = (float)acc[r][c] * sc;
                pk |= ((unsigned)(q8i(v, S_DT) & 255)) << (8 * r);
            }
            *(unsigned*)(dst + ((size_t)b * 4096 + j) * 2048 + s0) = pk;
        }
    } else {
        const float sc = S_Y * wsc;
        float* O = (float*)out0;
        const int j0 = n0 + (tx << 2);
        #pragma unroll
        for (int r = 0; r < 4; r++) {
            const int m = m0 + (ty << 2) + r;
            float4 v;
            v.x = (float)acc[r][0] * sc; v.y = (float)acc[r][1] * sc;
            v.z = (float)acc[r][2] * sc; v.w = (float)acc[r][3] * sc;
            *(float4*)(O + (size_t)m * N + j0) = v;
        }
    }
}

// ---------------- depthwise causal conv(K=4) + silu + quant ----------------
__global__ __launch_bounds__(256)
void k_conv(const i8* __restrict__ hsq, const i8* __restrict__ cwq,
            const float* __restrict__ conv_b, const unsigned* __restrict__ cmaxbits,
            i8* __restrict__ uq, i8* __restrict__ uqT) {
    __shared__ char lt[64][68];
    const int tid = threadIdx.x;
    const int b = blockIdx.z;
    const int d0 = blockIdx.y << 6;
    const int s0 = blockIdx.x << 6;
    const int dl = tid >> 2;
    const int sg = tid & 3;
    const int d = d0 + dl;
    const int sbase = s0 + (sg << 4);
    const i8* xp = hsq + ((size_t)b * 4096 + d) * 2048;
    int v[19];
    #pragma unroll
    for (int i = 0; i < 19; i++) {
        int s = sbase - 3 + i;
        v[i] = (s >= 0) ? (int)xp[s] : 0;
    }
    const unsigned cw = *(const unsigned*)(cwq + (size_t)d * 4);
    const int w0 = (int)(char)(cw & 255);
    const int w1 = (int)(char)((cw >> 8) & 255);
    const int w2 = (int)(char)((cw >> 16) & 255);
    const int w3 = (int)(char)((cw >> 24) & 255);
    const float cws = __uint_as_float(*cmaxbits) / 127.0f;
    const float sc = S_Z * cws;
    const float bias = conv_b[d];
    unsigned pk[4] = {0, 0, 0, 0};
    #pragma unroll
    for (int t = 0; t < 16; t++) {
        int acc = v[t] * w0 + v[t + 1] * w1 + v[t + 2] * w2 + v[t + 3] * w3;
        float f = __fadd_rn(__fmul_rn((float)acc, sc), bias);
        float sig = 1.0f / (1.0f + expf(-f));
        float sl = __fmul_rn(f, sig);           // silu
        int q = q8i(sl, S_U);
        pk[t >> 2] |= ((unsigned)(q & 255)) << ((t & 3) * 8);
        lt[(sg << 4) + t][dl] = (char)q;
    }
    *(int4*)(uq + ((size_t)b * 4096 + d) * 2048 + sbase) = make_int4(pk[0], pk[1], pk[2], pk[3]);
    __syncthreads();
    const int rr = tid >> 2;
    const int wg = tid & 3;
    const int* rp = (const int*)(&lt[rr][wg << 4]);
    int4 o; o.x = rp[0]; o.y = rp[1]; o.z = rp[2]; o.w = rp[3];
    *(int4*)(uqT + ((size_t)b * 2048 + s0 + rr) * 4096 + d0 + (wg << 4)) = o;
}

// ---------------- rmsnorm + quant for dt(128), B(16), C(16) ----------------
__global__ __launch_bounds__(64)
void k_rms(const float* __restrict__ p,
           const float* __restrict__ wdt, const float* __restrict__ wB, const float* __restrict__ wC,
           i8* __restrict__ dtq, i8* __restrict__ bq, i8* __restrict__ cq) {
    const int row = blockIdx.x;
    const int lane = threadIdx.x;
    const float* x = p + (size_t)row * 160;
    float a0 = x[lane], a1 = x[64 + lane];
    float bb = (lane < 16) ? x[128 + lane] : 0.0f;
    float cc = (lane < 16) ? x[144 + lane] : 0.0f;
    float sdt = __fadd_rn(__fmul_rn(a0, a0), __fmul_rn(a1, a1));
    float sB = __fmul_rn(bb, bb);
    float sC = __fmul_rn(cc, cc);
    #pragma unroll
    for (int off = 32; off; off >>= 1) {
        sdt = __fadd_rn(sdt, __shfl_xor(sdt, off));
        sB  = __fadd_rn(sB,  __shfl_xor(sB, off));
        sC  = __fadd_rn(sC,  __shfl_xor(sC, off));
    }
    float rdt = 1.0f / sqrtf(sdt / 128.0f + 1e-6f);
    float rB  = 1.0f / sqrtf(sB / 16.0f + 1e-6f);
    float rC  = 1.0f / sqrtf(sC / 16.0f + 1e-6f);
    dtq[(size_t)row * 128 + lane]      = (i8)q8i(__fmul_rn(wdt[lane],      __fmul_rn(a0, rdt)), S_DTLN);
    dtq[(size_t)row * 128 + 64 + lane] = (i8)q8i(__fmul_rn(wdt[64 + lane], __fmul_rn(a1, rdt)), S_DTLN);
    if (lane < 16) {
        bq[(size_t)row * 16 + lane] = (i8)q8i(__fmul_rn(wB[lane], __fmul_rn(bb, rB)), S_B);
        cq[(size_t)row * 16 + lane] = (i8)q8i(__fmul_rn(wC[lane], __fmul_rn(cc, rC)), S_C);
    }
}

// ---------------- LUT builders (bit-identical op sequences to the old scan) ----------------
// lut_dt[d][q] = softplus((float)(q-128)*S_DT + dt_bias[d])
__global__ __launch_bounds__(256)
void k_lut_dt(const float* __restrict__ dt_bias, float* __restrict__ lut) {
    const int d = blockIdx.x;
    const int q = threadIdx.x;
    const float bias = dt_bias[d];
    lut[(size_t)d * 256 + q] =
        softplus_f(__fadd_rn(__fmul_rn((float)(q - 128), S_DT), bias));
}
// lut_silu[q] = gv*sigmoid(gv), gv = (float)(q-128)*S_Z
__global__ __launch_bounds__(256)
void k_lut_silu(float* __restrict__ lut) {
    const int q = threadIdx.x;
    float gv = __fmul_rn((float)(q - 128), S_Z);
    float sg = __fmul_rn(gv, 1.0f / (1.0f + expf(-gv)));
    lut[q] = sg;
}

// ---------------- selective scan: lane per (b,d,n), 16-lane reduce, LUT-accelerated ----------------
__global__ __launch_bounds__(256)
void k_scan2(const i8* __restrict__ dt8, const i8* __restrict__ uq, const i8* __restrict__ gq,
             const i8* __restrict__ Bq, const i8* __restrict__ Cq,
             const float* __restrict__ lut_dt, const float* __restrict__ lut_silu,
             const float* __restrict__ A_log, const float* __restrict__ D_skip,
             i8* __restrict__ yq) {
    const int g = blockIdx.x * 256 + threadIdx.x;
    const int n = g & 15;
    const int bd = g >> 4;           // b*4096 + d
    const int d = bd & 4095;
    const int b = bd >> 12;
    const float Acoef = -expf(A_log[(size_t)d * 16 + n]);
    const float Dd = D_skip[d];
    const float* ldt = lut_dt + (size_t)d * 256;   // 1KB row, L1-resident
    const i8* dtp = dt8 + (size_t)bd * 2048;
    const i8* up  = uq  + (size_t)bd * 2048;
    const i8* gp  = gq  + (size_t)bd * 2048;
    const i8* Bp  = Bq + (size_t)b * 2048 * 16 + n;
    const i8* Cp  = Cq + (size_t)b * 2048 * 16 + n;
    i8* yp = yq + (size_t)b * 2048 * 4096 + d;
    float h = 0.0f;
    #pragma unroll 4
    for (int s = 0; s < 2048; s++) {
        float dtv = ldt[(int)dtp[s] + 128];               // == softplus(dt8*S_DT+bias), bit-exact
        float uv = __fmul_rn((float)up[s], S_U);
        float dA = expf(__fmul_rn(dtv, Acoef));
        float Bv = __fmul_rn((float)Bp[(size_t)s * 16], S_B);
        float Cv = __fmul_rn((float)Cp[(size_t)s * 16], S_C);
        h = __fadd_rn(__fmul_rn(h, dA), __fmul_rn(__fmul_rn(dtv, uv), Bv));
        float y = __fmul_rn(h, Cv);
        y = __fadd_rn(y, __shfl_xor(y, 1));
        y = __fadd_rn(y, __shfl_xor(y, 2));
        y = __fadd_rn(y, __shfl_xor(y, 4));
        y = __fadd_rn(y, __shfl_xor(y, 8));
        if (n == 0) {
            float ys = __fadd_rn(y, __fmul_rn(uv, Dd));
            float sg = lut_silu[(int)gp[s] + 128];        // == gv*sigmoid(gv), bit-exact
            float v = __fmul_rn(ys, sg);
            yp[(size_t)s * 4096] = (i8)q8i(v, S_Y);
        }
    }
}

extern "C" void kernel_launch(void* const* d_in, const int* in_sizes, int n_in,
                              void* d_out, int out_size, void* d_ws, size_t ws_size,
                              hipStream_t stream) {
    const float* hidden   = (const float*)d_in[0];   // (2,2048,2048) f32
    const float* in_proj  = (const float*)d_in[1];   // (8192,2048)
    const float* conv_w   = (const float*)d_in[2];   // (4096,4)
    const float* conv_b   = (const float*)d_in[3];   // (4096,)
    const float* x_proj   = (const float*)d_in[4];   // (160,4096)
    const float* dt_ln    = (const float*)d_in[5];
    const float* B_ln     = (const float*)d_in[6];
    const float* C_ln     = (const float*)d_in[7];
    const float* dt_proj  = (const float*)d_in[8];   // (4096,128)
    const float* dt_bias  = (const float*)d_in[9];
    const float* A_log    = (const float*)d_in[10];  // (4096,16)
    const float* D_skip   = (const float*)d_in[11];
    const float* out_proj = (const float*)d_in[12];  // (2048,4096)
    float* out = (float*)d_out;                      // (2,2048,2048) f32 = 33.55 MB

    // ---- workspace layout, 46,416,128 B total (same proven footprint) ----
    char* ws = (char*)d_ws;
    unsigned* scales = (unsigned*)ws;                       // 256 B
    i8* WQ   = (i8*)(ws + 256);                             // 16,777,216: in_proj q8 -> u_qT -> y_q
    i8* XQ   = (i8*)(ws + 16777472);                        //  8,388,608: x_q -> OWQ
    i8* HSQ  = (i8*)(ws + 25166080);                        // 16,777,216: hs_q -> dt8
    // S0 region: SSMP/DTQ/XWQ/DWQ/CWQ (all dead after GEMM3) -> reused as lut_dt
    char* S0 = ws + 41943296;
    float* SSMP = (float*)S0;                               // 2,621,440: ssm_p [4096][160]
    i8* DTQb = (i8*)(S0 + 2621440);                         //   524,288: dt_q [4096][128]
    i8* XWQ  = (i8*)(S0 + 3145728);                         //   655,360: x_proj q8
    i8* DWQ  = (i8*)(S0 + 3801088);                         //   524,288: dt_proj q8
    i8* CWQ  = (i8*)(S0 + 4325376);                         //    16,384: conv q8
    float* LUTDT = (float*)S0;                              // 4,194,304 (overlap; built after GEMM3)
    float* LUTSI = (float*)(S0 + 4194304);                  //     1,024 (overlaps dead CWQ tail zone)
    i8* BQ   = (i8*)(S0 + 4341760);                         //    65,536: B_q [2][2048][16]
    i8* CQ   = (i8*)(S0 + 4407296);                         //    65,536: C_q
    // end: 41,943,296 + 4,472,832 = 46,416,128

    // d_out doubles as scratch for the two scan-only 16.7MB tensors;
    // both fully rewritten every call, dead before GEMM4 writes d_out.
    i8* GQ = (i8*)d_out;                                    // gate_q [2][4096][2048]
    i8* UQ = (i8*)d_out + 16777216;                         // u_q    [2][4096][2048]
    i8* UQT = WQ;                                           // u_qT [2][2048][4096]
    i8* OWQ = XQ;                                           // out_proj q8 [2048][4096]
    i8* DT8 = HSQ;                                          // dt8 [2][4096][2048]
    i8* YQ  = WQ;                                           // y_q [2][2048][4096]

    hipMemsetAsync(scales, 0, 256, stream);

    k_maxabs<<<2048, 256, 0, stream>>>(in_proj, 16777216LL, scales + 0);
    k_maxabs<<<64,   256, 0, stream>>>(conv_w,  16384LL,    scales + 1);
    k_maxabs<<<512,  256, 0, stream>>>(x_proj,  655360LL,   scales + 2);
    k_maxabs<<<512,  256, 0, stream>>>(dt_proj, 524288LL,   scales + 3);
    k_maxabs<<<1024, 256, 0, stream>>>(out_proj, 8388608LL, scales + 4);

    k_quant_w<<<16384, 256, 0, stream>>>(in_proj, 16777216LL, scales + 0, WQ);
    k_quant_w<<<16,    256, 0, stream>>>(conv_w,  16384LL,    scales + 1, CWQ);
    k_quant_w<<<640,   256, 0, stream>>>(x_proj,  655360LL,   scales + 2, XWQ);
    k_quant_w<<<512,   256, 0, stream>>>(dt_proj, 524288LL,   scales + 3, DWQ);
    k_quant_x<<<8192,  256, 0, stream>>>(hidden,  8388608LL,  S_IN, XQ);

    // GEMM1: proj = x_q[4096x2048] @ in_proj^T -> hs_q(HSQ) / gate_q(GQ), int8 [b,d,s]
    dim3 g1(128, 64);
    k_gemm<0><<<g1, 256, 0, stream>>>(XQ, WQ, 4096, 8192, 2048, scales + 0, HSQ, GQ);

    // x_q dead -> quantize out_proj into XQ region
    k_quant_w<<<8192, 256, 0, stream>>>(out_proj, 8388608LL, scales + 4, OWQ);

    // conv + silu + quant: hs_q -> u_q(UQ,[b,d,s]) and u_qT(WQ region,[b,s,d])
    dim3 gc(32, 64, 2);
    k_conv<<<gc, 256, 0, stream>>>(HSQ, CWQ, conv_b, scales + 1, UQ, UQT);

    // GEMM2: ssm_p = u_qT[4096x4096] @ x_proj^T[4096x160] -> f32
    dim3 g2(3, 64);
    k_gemm<1><<<g2, 256, 0, stream>>>(UQT, XWQ, 4096, 160, 4096, scales + 2, SSMP, nullptr);

    k_rms<<<4096, 64, 0, stream>>>(SSMP, dt_ln, B_ln, C_ln, DTQb, BQ, CQ);

    // GEMM3: dt8 = dt_q[4096x128] @ dt_proj^T[128x4096] -> int8 [b,d,s] into HSQ
    dim3 g3(64, 64);
    k_gemm<2><<<g3, 256, 0, stream>>>(DTQb, DWQ, 4096, 4096, 128, scales + 3, DT8, nullptr);

    // LUTs (SSMP/DTQ/XWQ/DWQ/CWQ all dead now)
    k_lut_dt<<<4096, 256, 0, stream>>>(dt_bias, LUTDT);
    k_lut_silu<<<1, 256, 0, stream>>>(LUTSI);

    // scan: -> y_q [b,s,d] into WQ region
    k_scan2<<<512, 256, 0, stream>>>(DT8, UQ, GQ, BQ, CQ, LUTDT, LUTSI, A_log, D_skip, YQ);

    // GEMM4: out = y_q[4096x4096] @ out_proj^T[4096x2048] -> f32
    dim3 g4(32, 64);
    k_gemm<3><<<g4, 256, 0, stream>>>(YQ, OWQ, 4096, 2048, 4096, scales + 4, out, nullptr);
}

// Round 6
// 1270.639 us; speedup vs baseline: 2.4704x; 1.9680x over previous
//
#include <hip/hip_runtime.h>
#include <stdint.h>

typedef signed char i8;
typedef int v4i __attribute__((ext_vector_type(4)));

#define S_IN  0.05f
#define S_Z   0.02f
#define S_U   0.01f
#define S_DTLN 0.02f
#define S_B   0.02f
#define S_C   0.02f
#define S_DT  0.01f
#define S_Y   0.01f

__device__ __forceinline__ int dot4(int a, int b, int c) {
    return __builtin_amdgcn_sdot4(a, b, c, false);
}

// qa(): round-half-even (matches jnp.round), clip to [-128,127]
__device__ __forceinline__ float q8f(float x, float s) {
    float r = rintf(x / s);
    return fmaxf(-128.0f, fminf(127.0f, r));
}
__device__ __forceinline__ int q8i(float x, float s) { return (int)q8f(x, s); }

__device__ __forceinline__ float softplus_f(float x) {
    return __fadd_rn(fmaxf(x, 0.0f), log1pf(expf(-fabsf(x))));
}

__device__ __forceinline__ int sbyte_of(int w, int j) {
    return (int)(signed char)((unsigned)w >> (j * 8));
}

// ---------------- max|w| reduction ----------------
__global__ __launch_bounds__(256)
void k_maxabs(const float* __restrict__ w, long long n, unsigned* __restrict__ out) {
    unsigned m = 0;
    long long stride = (long long)gridDim.x * 256;
    for (long long i = (long long)blockIdx.x * 256 + threadIdx.x; i < n; i += stride)
        m = max(m, __float_as_uint(fabsf(w[i])));
    #pragma unroll
    for (int off = 32; off; off >>= 1) {
        unsigned o = (unsigned)__shfl_xor((int)m, off);
        m = max(m, o);
    }
    __shared__ unsigned sm[4];
    if ((threadIdx.x & 63) == 0) sm[threadIdx.x >> 6] = m;
    __syncthreads();
    if (threadIdx.x == 0) {
        unsigned r = max(max(sm[0], sm[1]), max(sm[2], sm[3]));
        atomicMax(out, r);
    }
}

// ---------------- weight quant ----------------
__global__ __launch_bounds__(256)
void k_quant_w(const float* __restrict__ w, long long n,
               const unsigned* __restrict__ maxbits, i8* __restrict__ o) {
    long long i = ((long long)blockIdx.x * 256 + threadIdx.x) * 4;
    if (i >= n) return;
    float s = __uint_as_float(*maxbits) / 127.0f;
    float4 v = *(const float4*)(w + i);
    unsigned pk = ((unsigned)(q8i(v.x, s) & 255))
                | ((unsigned)(q8i(v.y, s) & 255) << 8)
                | ((unsigned)(q8i(v.z, s) & 255) << 16)
                | ((unsigned)(q8i(v.w, s) & 255) << 24);
    *(unsigned*)(o + i) = pk;
}

// ---------------- activation quant ----------------
__global__ __launch_bounds__(256)
void k_quant_x(const float* __restrict__ x, long long n, float s, i8* __restrict__ o) {
    long long i = ((long long)blockIdx.x * 256 + threadIdx.x) * 4;
    if (i >= n) return;
    float4 v = *(const float4*)(x + i);
    unsigned pk = ((unsigned)(q8i(v.x, s) & 255))
                | ((unsigned)(q8i(v.y, s) & 255) << 8)
                | ((unsigned)(q8i(v.z, s) & 255) << 16)
                | ((unsigned)(q8i(v.w, s) & 255) << 24);
    *(unsigned*)(o + i) = pk;
}

// ---------------- dot4 GEMM (kept for EPI1: N=160 ragged) ----------------
template<int EPI>
__global__ __launch_bounds__(256)
void k_gemm(const i8* __restrict__ A, const i8* __restrict__ Bw,
            int M, int N, int K,
            const unsigned* __restrict__ wmaxbits,
            void* __restrict__ out0, void* __restrict__ out1) {
    __shared__ int As[64][17];
    __shared__ int Bs[64][17];
    const int tid = threadIdx.x;
    const int m0 = blockIdx.y << 6;
    const int n0 = blockIdx.x << 6;
    const int tx = tid & 15;
    const int ty = tid >> 4;
    const int ldr = tid >> 2;
    const int ldw = (tid & 3) << 2;
    int acc[4][4] = {};
    for (int k0 = 0; k0 < K; k0 += 64) {
        int4 av = *(const int4*)(A + (size_t)(m0 + ldr) * K + k0 + (ldw << 2));
        int4 bv = make_int4(0, 0, 0, 0);
        if (n0 + ldr < N)
            bv = *(const int4*)(Bw + (size_t)(n0 + ldr) * K + k0 + (ldw << 2));
        As[ldr][ldw + 0] = av.x; As[ldr][ldw + 1] = av.y;
        As[ldr][ldw + 2] = av.z; As[ldr][ldw + 3] = av.w;
        Bs[ldr][ldw + 0] = bv.x; Bs[ldr][ldw + 1] = bv.y;
        Bs[ldr][ldw + 2] = bv.z; Bs[ldr][ldw + 3] = bv.w;
        __syncthreads();
        #pragma unroll
        for (int kk = 0; kk < 16; kk++) {
            const int a0 = As[(ty << 2) + 0][kk];
            const int a1 = As[(ty << 2) + 1][kk];
            const int a2 = As[(ty << 2) + 2][kk];
            const int a3 = As[(ty << 2) + 3][kk];
            const int b0 = Bs[(tx << 2) + 0][kk];
            const int b1 = Bs[(tx << 2) + 1][kk];
            const int b2 = Bs[(tx << 2) + 2][kk];
            const int b3 = Bs[(tx << 2) + 3][kk];
            acc[0][0] = dot4(a0, b0, acc[0][0]); acc[0][1] = dot4(a0, b1, acc[0][1]);
            acc[0][2] = dot4(a0, b2, acc[0][2]); acc[0][3] = dot4(a0, b3, acc[0][3]);
            acc[1][0] = dot4(a1, b0, acc[1][0]); acc[1][1] = dot4(a1, b1, acc[1][1]);
            acc[1][2] = dot4(a1, b2, acc[1][2]); acc[1][3] = dot4(a1, b3, acc[1][3]);
            acc[2][0] = dot4(a2, b0, acc[2][0]); acc[2][1] = dot4(a2, b1, acc[2][1]);
            acc[2][2] = dot4(a2, b2, acc[2][2]); acc[2][3] = dot4(a2, b3, acc[2][3]);
            acc[3][0] = dot4(a3, b0, acc[3][0]); acc[3][1] = dot4(a3, b1, acc[3][1]);
            acc[3][2] = dot4(a3, b2, acc[3][2]); acc[3][3] = dot4(a3, b3, acc[3][3]);
        }
        __syncthreads();
    }
    const float wsc = __uint_as_float(*wmaxbits) / 127.0f;
    if constexpr (EPI == 1) {
        const float sc = S_U * wsc;
        float* O = (float*)out0;
        const int j0 = n0 + (tx << 2);
        #pragma unroll
        for (int r = 0; r < 4; r++) {
            const int m = m0 + (ty << 2) + r;
            if (j0 + 3 < N) {
                float4 v;
                v.x = (float)acc[r][0] * sc; v.y = (float)acc[r][1] * sc;
                v.z = (float)acc[r][2] * sc; v.w = (float)acc[r][3] * sc;
                *(float4*)(O + (size_t)m * N + j0) = v;
            } else {
                for (int c = 0; c < 4; c++)
                    if (j0 + c < N) O[(size_t)m * N + j0 + c] = (float)acc[r][c] * sc;
            }
        }
    }
}

// ---------------- MFMA int8 GEMM: C[M,N] = A[M,K] * Bw[N,K]^T ----------------
// 128x128 block, 4 waves (2x2), each wave 64x64 = 4x4 tiles of 16x16, K-step 32.
// EPI 0: -> int8 transposed split hs/gate; EPI 2: -> int8 transposed dt8; EPI 3: f32 out.
template<int EPI>
__global__ __launch_bounds__(256)
void k_mgemm(const i8* __restrict__ A, const i8* __restrict__ Bw,
             int M, int N, int K,
             const unsigned* __restrict__ wmaxbits,
             void* __restrict__ out0, void* __restrict__ out1) {
    const int tid = threadIdx.x;
    const int w = tid >> 6;
    const int l = tid & 63;
    const int m0 = (blockIdx.y << 7) + ((w >> 1) << 6);
    const int n0 = (blockIdx.x << 7) + ((w & 1) << 6);
    const int lr = l & 15;          // row (A) / col (B) within 16-tile
    const int lk = l >> 4;          // k-chunk 0..3 (8 bytes each)
    const i8* ap = A  + (size_t)(m0 + lr) * K + lk * 8;
    const i8* bp = Bw + (size_t)(n0 + lr) * K + lk * 8;
    v4i acc[4][4] = {};
    long ac[4], bc[4], an[4], bn[4];
    #pragma unroll
    for (int i = 0; i < 4; i++) {
        ac[i] = *(const long*)(ap + (size_t)i * 16 * K);
        bc[i] = *(const long*)(bp + (size_t)i * 16 * K);
    }
    for (int k0 = 0; k0 < K; k0 += 32) {
        if (k0 + 32 < K) {
            #pragma unroll
            for (int i = 0; i < 4; i++) {
                an[i] = *(const long*)(ap + (size_t)i * 16 * K + k0 + 32);
                bn[i] = *(const long*)(bp + (size_t)i * 16 * K + k0 + 32);
            }
        }
        #pragma unroll
        for (int mt = 0; mt < 4; mt++)
            #pragma unroll
            for (int nt = 0; nt < 4; nt++)
                acc[mt][nt] = __builtin_amdgcn_mfma_i32_16x16x32_i8(ac[mt], bn ? bc[nt] : bc[nt], acc[mt][nt], 0, 0, 0);
        if (k0 + 32 < K) {
            #pragma unroll
            for (int i = 0; i < 4; i++) { ac[i] = an[i]; bc[i] = bn[i]; }
        }
    }
    const float wsc = __uint_as_float(*wmaxbits) / 127.0f;
    // D layout (m89-verified): lane l, reg r -> row = base + (l>>4)*4 + r, col = base + (l&15)
    if constexpr (EPI == 0 || EPI == 2) {
        const float sc = (EPI == 0 ? S_IN : S_DTLN) * wsc;
        const float qs = (EPI == 0 ? S_Z : S_DT);
        const int b = m0 >> 11;
        #pragma unroll
        for (int nt = 0; nt < 4; nt++) {
            const int j = n0 + nt * 16 + lr;
            i8* dst;
            if constexpr (EPI == 0) dst = (j < 4096) ? (i8*)out0 : (i8*)out1;
            else dst = (i8*)out0;
            const int jj = j & 4095;
            #pragma unroll
            for (int mt = 0; mt < 4; mt++) {
                const int sbase = (m0 & 2047) + mt * 16 + lk * 4;
                unsigned pk = 0;
                #pragma unroll
                for (int r = 0; r < 4; r++) {
                    float v = (float)acc[mt][nt][r] * sc;
                    pk |= ((unsigned)(q8i(v, qs) & 255)) << (8 * r);
                }
                *(unsigned*)(dst + ((size_t)b * 4096 + jj) * 2048 + sbase) = pk;
            }
        }
    } else {
        const float sc = S_Y * wsc;
        float* O = (float*)out0;
        #pragma unroll
        for (int mt = 0; mt < 4; mt++)
            #pragma unroll
            for (int r = 0; r < 4; r++) {
                const int m = m0 + mt * 16 + lk * 4 + r;
                #pragma unroll
                for (int nt = 0; nt < 4; nt++)
                    O[(size_t)m * N + n0 + nt * 16 + lr] = (float)acc[mt][nt][r] * sc;
            }
    }
}

// ---------------- depthwise causal conv(K=4) + silu + quant ----------------
__global__ __launch_bounds__(256)
void k_conv(const i8* __restrict__ hsq, const i8* __restrict__ cwq,
            const float* __restrict__ conv_b, const unsigned* __restrict__ cmaxbits,
            i8* __restrict__ uq, i8* __restrict__ uqT) {
    __shared__ char lt[64][68];
    const int tid = threadIdx.x;
    const int b = blockIdx.z;
    const int d0 = blockIdx.y << 6;
    const int s0 = blockIdx.x << 6;
    const int dl = tid >> 2;
    const int sg = tid & 3;
    const int d = d0 + dl;
    const int sbase = s0 + (sg << 4);
    const i8* xp = hsq + ((size_t)b * 4096 + d) * 2048;
    int v[19];
    #pragma unroll
    for (int i = 0; i < 19; i++) {
        int s = sbase - 3 + i;
        v[i] = (s >= 0) ? (int)xp[s] : 0;
    }
    const unsigned cw = *(const unsigned*)(cwq + (size_t)d * 4);
    const int w0 = (int)(char)(cw & 255);
    const int w1 = (int)(char)((cw >> 8) & 255);
    const int w2 = (int)(char)((cw >> 16) & 255);
    const int w3 = (int)(char)((cw >> 24) & 255);
    const float cws = __uint_as_float(*cmaxbits) / 127.0f;
    const float sc = S_Z * cws;
    const float bias = conv_b[d];
    unsigned pk[4] = {0, 0, 0, 0};
    #pragma unroll
    for (int t = 0; t < 16; t++) {
        int acc = v[t] * w0 + v[t + 1] * w1 + v[t + 2] * w2 + v[t + 3] * w3;
        float f = __fadd_rn(__fmul_rn((float)acc, sc), bias);
        float sig = 1.0f / (1.0f + expf(-f));
        float sl = __fmul_rn(f, sig);
        int q = q8i(sl, S_U);
        pk[t >> 2] |= ((unsigned)(q & 255)) << ((t & 3) * 8);
        lt[(sg << 4) + t][dl] = (char)q;
    }
    *(int4*)(uq + ((size_t)b * 4096 + d) * 2048 + sbase) = make_int4(pk[0], pk[1], pk[2], pk[3]);
    __syncthreads();
    const int rr = tid >> 2;
    const int wg = tid & 3;
    const int* rp = (const int*)(&lt[rr][wg << 4]);
    int4 o; o.x = rp[0]; o.y = rp[1]; o.z = rp[2]; o.w = rp[3];
    *(int4*)(uqT + ((size_t)b * 2048 + s0 + rr) * 4096 + d0 + (wg << 4)) = o;
}

// ---------------- rmsnorm + quant; B/C written TRANSPOSED [b][n][s] ----------------
__global__ __launch_bounds__(64)
void k_rms(const float* __restrict__ p,
           const float* __restrict__ wdt, const float* __restrict__ wB, const float* __restrict__ wC,
           i8* __restrict__ dtq, i8* __restrict__ bqT, i8* __restrict__ cqT) {
    const int row = blockIdx.x;
    const int lane = threadIdx.x;
    const float* x = p + (size_t)row * 160;
    float a0 = x[lane], a1 = x[64 + lane];
    float bb = (lane < 16) ? x[128 + lane] : 0.0f;
    float cc = (lane < 16) ? x[144 + lane] : 0.0f;
    float sdt = __fadd_rn(__fmul_rn(a0, a0), __fmul_rn(a1, a1));
    float sB = __fmul_rn(bb, bb);
    float sC = __fmul_rn(cc, cc);
    #pragma unroll
    for (int off = 32; off; off >>= 1) {
        sdt = __fadd_rn(sdt, __shfl_xor(sdt, off));
        sB  = __fadd_rn(sB,  __shfl_xor(sB, off));
        sC  = __fadd_rn(sC,  __shfl_xor(sC, off));
    }
    float rdt = 1.0f / sqrtf(sdt / 128.0f + 1e-6f);
    float rB  = 1.0f / sqrtf(sB / 16.0f + 1e-6f);
    float rC  = 1.0f / sqrtf(sC / 16.0f + 1e-6f);
    dtq[(size_t)row * 128 + lane]      = (i8)q8i(__fmul_rn(wdt[lane],      __fmul_rn(a0, rdt)), S_DTLN);
    dtq[(size_t)row * 128 + 64 + lane] = (i8)q8i(__fmul_rn(wdt[64 + lane], __fmul_rn(a1, rdt)), S_DTLN);
    if (lane < 16) {
        size_t tpos = ((size_t)(row >> 11) * 16 + lane) * 2048 + (row & 2047);
        bqT[tpos] = (i8)q8i(__fmul_rn(wB[lane], __fmul_rn(bb, rB)), S_B);
        cqT[tpos] = (i8)q8i(__fmul_rn(wC[lane], __fmul_rn(cc, rC)), S_C);
    }
}

// ---------------- LUT builders (bit-identical op sequences) ----------------
__global__ __launch_bounds__(256)
void k_lut_dt(const float* __restrict__ dt_bias, float* __restrict__ lut) {
    const int d = blockIdx.x;
    const int q = threadIdx.x;
    const float bias = dt_bias[d];
    lut[(size_t)d * 256 + q] =
        softplus_f(__fadd_rn(__fmul_rn((float)(q - 128), S_DT), bias));
}
__global__ __launch_bounds__(256)
void k_lut_silu(float* __restrict__ lut) {
    const int q = threadIdx.x;
    float gv = __fmul_rn((float)(q - 128), S_Z);
    float sg = __fmul_rn(gv, 1.0f / (1.0f + expf(-gv)));
    lut[q] = sg;
}

// ---------------- scan v3: 16-step tiles, vector loads, batched LUT/expf ----------------
__global__ __launch_bounds__(256)
void k_scan3(const i8* __restrict__ dt8, const i8* __restrict__ uq, const i8* __restrict__ gq,
             const i8* __restrict__ BqT, const i8* __restrict__ CqT,
             const float* __restrict__ lut_dt, const float* __restrict__ lut_silu,
             const float* __restrict__ A_log, const float* __restrict__ D_skip,
             i8* __restrict__ yq) {
    const int g = blockIdx.x * 256 + threadIdx.x;
    const int n = g & 15;
    const int bd = g >> 4;
    const int d = bd & 4095;
    const int b = bd >> 12;
    const float Acoef = -expf(A_log[(size_t)d * 16 + n]);
    const float Dd = D_skip[d];
    const float* ldt = lut_dt + (size_t)d * 256;
    const v4i* dtp = (const v4i*)(dt8 + (size_t)bd * 2048);
    const v4i* up  = (const v4i*)(uq  + (size_t)bd * 2048);
    const v4i* gp  = (const v4i*)(gq  + (size_t)bd * 2048);
    const v4i* Bp  = (const v4i*)(BqT + ((size_t)b * 16 + n) * 2048);
    const v4i* Cp  = (const v4i*)(CqT + ((size_t)b * 16 + n) * 2048);
    i8* yp = yq + (size_t)b * 2048 * 4096 + d;
    float h = 0.0f;
    v4i dtw = dtp[0], uw = up[0], gw = gp[0], bw = Bp[0], cw = Cp[0];
    for (int t = 0; t < 128; t++) {
        v4i ndt, nu, ng, nb, nc;
        if (t < 127) { ndt = dtp[t + 1]; nu = up[t + 1]; ng = gp[t + 1]; nb = Bp[t + 1]; nc = Cp[t + 1]; }
        float dtv[16], dA[16];
        #pragma unroll
        for (int j = 0; j < 16; j++)
            dtv[j] = ldt[sbyte_of(dtw[j >> 2], j & 3) + 128];
        #pragma unroll
        for (int j = 0; j < 16; j++)
            dA[j] = expf(__fmul_rn(dtv[j], Acoef));
        float ysave = 0.0f;
        #pragma unroll
        for (int j = 0; j < 16; j++) {
            float uv = __fmul_rn((float)sbyte_of(uw[j >> 2], j & 3), S_U);
            float Bv = __fmul_rn((float)sbyte_of(bw[j >> 2], j & 3), S_B);
            float Cv = __fmul_rn((float)sbyte_of(cw[j >> 2], j & 3), S_C);
            h = __fadd_rn(__fmul_rn(h, dA[j]), __fmul_rn(__fmul_rn(dtv[j], uv), Bv));
            float y = __fmul_rn(h, Cv);
            y = __fadd_rn(y, __shfl_xor(y, 1));
            y = __fadd_rn(y, __shfl_xor(y, 2));
            y = __fadd_rn(y, __shfl_xor(y, 4));
            y = __fadd_rn(y, __shfl_xor(y, 8));
            if (j == n) ysave = y;   // all lanes hold the bit-identical sum
        }
        // epilogue: lane n handles s = t*16 + n (same ops as before, all lanes active)
        int uws = (n & 8) ? ((n & 4) ? uw[3] : uw[2]) : ((n & 4) ? uw[1] : uw[0]);
        int gws = (n & 8) ? ((n & 4) ? gw[3] : gw[2]) : ((n & 4) ? gw[1] : gw[0]);
        float uvn = __fmul_rn((float)(int)(signed char)((unsigned)uws >> ((n & 3) * 8)), S_U);
        int gb = (int)(signed char)((unsigned)gws >> ((n & 3) * 8));
        float ys = __fadd_rn(ysave, __fmul_rn(uvn, Dd));
        float sg = lut_silu[gb + 128];
        float vv = __fmul_rn(ys, sg);
        yp[(size_t)(t * 16 + n) * 4096] = (i8)q8i(vv, S_Y);
        if (t < 127) { dtw = ndt; uw = nu; gw = ng; bw = nb; cw = nc; }
    }
}

extern "C" void kernel_launch(void* const* d_in, const int* in_sizes, int n_in,
                              void* d_out, int out_size, void* d_ws, size_t ws_size,
                              hipStream_t stream) {
    const float* hidden   = (const float*)d_in[0];
    const float* in_proj  = (const float*)d_in[1];
    const float* conv_w   = (const float*)d_in[2];
    const float* conv_b   = (const float*)d_in[3];
    const float* x_proj   = (const float*)d_in[4];
    const float* dt_ln    = (const float*)d_in[5];
    const float* B_ln     = (const float*)d_in[6];
    const float* C_ln     = (const float*)d_in[7];
    const float* dt_proj  = (const float*)d_in[8];
    const float* dt_bias  = (const float*)d_in[9];
    const float* A_log    = (const float*)d_in[10];
    const float* D_skip   = (const float*)d_in[11];
    const float* out_proj = (const float*)d_in[12];
    float* out = (float*)d_out;

    // ---- workspace layout, 46,416,128 B (proven footprint) ----
    char* ws = (char*)d_ws;
    unsigned* scales = (unsigned*)ws;                       // 256 B
    i8* WQ   = (i8*)(ws + 256);                             // 16,777,216: in_proj q8 -> u_qT -> y_q
    i8* XQ   = (i8*)(ws + 16777472);                        //  8,388,608: x_q -> OWQ
    i8* HSQ  = (i8*)(ws + 25166080);                        // 16,777,216: hs_q -> dt8
    char* S0 = ws + 41943296;
    float* SSMP = (float*)S0;                               // 2,621,440: ssm_p
    i8* DTQb = (i8*)(S0 + 2621440);                         //   524,288: dt_q
    i8* XWQ  = (i8*)(S0 + 3145728);                         //   655,360
    i8* DWQ  = (i8*)(S0 + 3801088);                         //   524,288
    i8* CWQ  = (i8*)(S0 + 4325376);                         //    16,384
    float* LUTDT = (float*)S0;                              // 4,194,304 (built after GEMM3)
    float* LUTSI = (float*)(S0 + 4194304);                  //     1,024
    i8* BQT  = (i8*)(S0 + 4341760);                         //    65,536: B_q^T [2][16][2048]
    i8* CQT  = (i8*)(S0 + 4407296);                         //    65,536: C_q^T

    i8* GQ = (i8*)d_out;                                    // gate_q [2][4096][2048]
    i8* UQ = (i8*)d_out + 16777216;                         // u_q    [2][4096][2048]
    i8* UQT = WQ;                                           // u_qT [2][2048][4096]
    i8* OWQ = XQ;                                           // out_proj q8
    i8* DT8 = HSQ;                                          // dt8 [2][4096][2048]
    i8* YQ  = WQ;                                           // y_q [2][2048][4096]

    hipMemsetAsync(scales, 0, 256, stream);

    k_maxabs<<<2048, 256, 0, stream>>>(in_proj, 16777216LL, scales + 0);
    k_maxabs<<<64,   256, 0, stream>>>(conv_w,  16384LL,    scales + 1);
    k_maxabs<<<512,  256, 0, stream>>>(x_proj,  655360LL,   scales + 2);
    k_maxabs<<<512,  256, 0, stream>>>(dt_proj, 524288LL,   scales + 3);
    k_maxabs<<<1024, 256, 0, stream>>>(out_proj, 8388608LL, scales + 4);

    k_quant_w<<<16384, 256, 0, stream>>>(in_proj, 16777216LL, scales + 0, WQ);
    k_quant_w<<<16,    256, 0, stream>>>(conv_w,  16384LL,    scales + 1, CWQ);
    k_quant_w<<<640,   256, 0, stream>>>(x_proj,  655360LL,   scales + 2, XWQ);
    k_quant_w<<<512,   256, 0, stream>>>(dt_proj, 524288LL,   scales + 3, DWQ);
    k_quant_x<<<8192,  256, 0, stream>>>(hidden,  8388608LL,  S_IN, XQ);

    // GEMM1 (MFMA): proj -> hs_q(HSQ) / gate_q(GQ), int8 [b,d,s]
    k_mgemm<0><<<dim3(64, 32), 256, 0, stream>>>(XQ, WQ, 4096, 8192, 2048, scales + 0, HSQ, GQ);

    k_quant_w<<<8192, 256, 0, stream>>>(out_proj, 8388608LL, scales + 4, OWQ);

    dim3 gc(32, 64, 2);
    k_conv<<<gc, 256, 0, stream>>>(HSQ, CWQ, conv_b, scales + 1, UQ, UQT);

    // GEMM2 (dot4, N=160): ssm_p
    dim3 g2(3, 64);
    k_gemm<1><<<g2, 256, 0, stream>>>(UQT, XWQ, 4096, 160, 4096, scales + 2, SSMP, nullptr);

    k_rms<<<4096, 64, 0, stream>>>(SSMP, dt_ln, B_ln, C_ln, DTQb, BQT, CQT);

    // GEMM3 (MFMA): dt8 -> [b,d,s] into HSQ
    k_mgemm<2><<<dim3(32, 32), 256, 0, stream>>>(DTQb, DWQ, 4096, 4096, 128, scales + 3, DT8, nullptr);

    k_lut_dt<<<4096, 256, 0, stream>>>(dt_bias, LUTDT);
    k_lut_silu<<<1, 256, 0, stream>>>(LUTSI);

    k_scan3<<<512, 256, 0, stream>>>(DT8, UQ, GQ, BQT, CQT, LUTDT, LUTSI, A_log, D_skip, YQ);

    // GEMM4 (MFMA): out = y_q @ out_proj^T -> f32
    k_mgemm<3><<<dim3(16, 32), 256, 0, stream>>>(YQ, OWQ, 4096, 2048, 4096, scales + 4, out, nullptr);
}

// Round 7
// 787.799 us; speedup vs baseline: 3.9845x; 1.6129x over previous
//
#include <hip/hip_runtime.h>
#include <stdint.h>

typedef signed char i8;
typedef int v4i __attribute__((ext_vector_type(4)));

#define S_IN  0.05f
#define S_Z   0.02f
#define S_U   0.01f
#define S_DTLN 0.02f
#define S_B   0.02f
#define S_C   0.02f
#define S_DT  0.01f
#define S_Y   0.01f

__device__ __forceinline__ int dot4(int a, int b, int c) {
    return __builtin_amdgcn_sdot4(a, b, c, false);
}

// qa(): round-half-even (matches jnp.round), clip to [-128,127]
__device__ __forceinline__ float q8f(float x, float s) {
    float r = rintf(x / s);
    return fmaxf(-128.0f, fminf(127.0f, r));
}
__device__ __forceinline__ int q8i(float x, float s) { return (int)q8f(x, s); }

__device__ __forceinline__ float softplus_f(float x) {
    return __fadd_rn(fmaxf(x, 0.0f), log1pf(expf(-fabsf(x))));
}

__device__ __forceinline__ int sbyte_of(int w, int j) {
    return (int)(signed char)((unsigned)w >> (j * 8));
}

// async global->LDS, 16B per lane; LDS dest = base + lane*16 (wave-uniform base)
__device__ __forceinline__ void gload16(const i8* g, i8* lds) {
    __builtin_amdgcn_global_load_lds(
        (const __attribute__((address_space(1))) unsigned int*)g,
        (__attribute__((address_space(3))) unsigned int*)lds,
        16, 0, 0);
}

// ---------------- max|w| reduction ----------------
__global__ __launch_bounds__(256)
void k_maxabs(const float* __restrict__ w, long long n, unsigned* __restrict__ out) {
    unsigned m = 0;
    long long stride = (long long)gridDim.x * 256;
    for (long long i = (long long)blockIdx.x * 256 + threadIdx.x; i < n; i += stride)
        m = max(m, __float_as_uint(fabsf(w[i])));
    #pragma unroll
    for (int off = 32; off; off >>= 1) {
        unsigned o = (unsigned)__shfl_xor((int)m, off);
        m = max(m, o);
    }
    __shared__ unsigned sm[4];
    if ((threadIdx.x & 63) == 0) sm[threadIdx.x >> 6] = m;
    __syncthreads();
    if (threadIdx.x == 0) {
        unsigned r = max(max(sm[0], sm[1]), max(sm[2], sm[3]));
        atomicMax(out, r);
    }
}

// ---------------- weight quant ----------------
__global__ __launch_bounds__(256)
void k_quant_w(const float* __restrict__ w, long long n,
               const unsigned* __restrict__ maxbits, i8* __restrict__ o) {
    long long i = ((long long)blockIdx.x * 256 + threadIdx.x) * 4;
    if (i >= n) return;
    float s = __uint_as_float(*maxbits) / 127.0f;
    float4 v = *(const float4*)(w + i);
    unsigned pk = ((unsigned)(q8i(v.x, s) & 255))
                | ((unsigned)(q8i(v.y, s) & 255) << 8)
                | ((unsigned)(q8i(v.z, s) & 255) << 16)
                | ((unsigned)(q8i(v.w, s) & 255) << 24);
    *(unsigned*)(o + i) = pk;
}

// ---------------- activation quant ----------------
__global__ __launch_bounds__(256)
void k_quant_x(const float* __restrict__ x, long long n, float s, i8* __restrict__ o) {
    long long i = ((long long)blockIdx.x * 256 + threadIdx.x) * 4;
    if (i >= n) return;
    float4 v = *(const float4*)(x + i);
    unsigned pk = ((unsigned)(q8i(v.x, s) & 255))
                | ((unsigned)(q8i(v.y, s) & 255) << 8)
                | ((unsigned)(q8i(v.z, s) & 255) << 16)
                | ((unsigned)(q8i(v.w, s) & 255) << 24);
    *(unsigned*)(o + i) = pk;
}

// ---------------- dot4 GEMM (kept for EPI1: N=160 ragged) ----------------
template<int EPI>
__global__ __launch_bounds__(256)
void k_gemm(const i8* __restrict__ A, const i8* __restrict__ Bw,
            int M, int N, int K,
            const unsigned* __restrict__ wmaxbits,
            void* __restrict__ out0, void* __restrict__ out1) {
    __shared__ int As[64][17];
    __shared__ int Bs[64][17];
    const int tid = threadIdx.x;
    const int m0 = blockIdx.y << 6;
    const int n0 = blockIdx.x << 6;
    const int tx = tid & 15;
    const int ty = tid >> 4;
    const int ldr = tid >> 2;
    const int ldw = (tid & 3) << 2;
    int acc[4][4] = {};
    for (int k0 = 0; k0 < K; k0 += 64) {
        int4 av = *(const int4*)(A + (size_t)(m0 + ldr) * K + k0 + (ldw << 2));
        int4 bv = make_int4(0, 0, 0, 0);
        if (n0 + ldr < N)
            bv = *(const int4*)(Bw + (size_t)(n0 + ldr) * K + k0 + (ldw << 2));
        As[ldr][ldw + 0] = av.x; As[ldr][ldw + 1] = av.y;
        As[ldr][ldw + 2] = av.z; As[ldr][ldw + 3] = av.w;
        Bs[ldr][ldw + 0] = bv.x; Bs[ldr][ldw + 1] = bv.y;
        Bs[ldr][ldw + 2] = bv.z; Bs[ldr][ldw + 3] = bv.w;
        __syncthreads();
        #pragma unroll
        for (int kk = 0; kk < 16; kk++) {
            const int a0 = As[(ty << 2) + 0][kk];
            const int a1 = As[(ty << 2) + 1][kk];
            const int a2 = As[(ty << 2) + 2][kk];
            const int a3 = As[(ty << 2) + 3][kk];
            const int b0 = Bs[(tx << 2) + 0][kk];
            const int b1 = Bs[(tx << 2) + 1][kk];
            const int b2 = Bs[(tx << 2) + 2][kk];
            const int b3 = Bs[(tx << 2) + 3][kk];
            acc[0][0] = dot4(a0, b0, acc[0][0]); acc[0][1] = dot4(a0, b1, acc[0][1]);
            acc[0][2] = dot4(a0, b2, acc[0][2]); acc[0][3] = dot4(a0, b3, acc[0][3]);
            acc[1][0] = dot4(a1, b0, acc[1][0]); acc[1][1] = dot4(a1, b1, acc[1][1]);
            acc[1][2] = dot4(a1, b2, acc[1][2]); acc[1][3] = dot4(a1, b3, acc[1][3]);
            acc[2][0] = dot4(a2, b0, acc[2][0]); acc[2][1] = dot4(a2, b1, acc[2][1]);
            acc[2][2] = dot4(a2, b2, acc[2][2]); acc[2][3] = dot4(a2, b3, acc[2][3]);
            acc[3][0] = dot4(a3, b0, acc[3][0]); acc[3][1] = dot4(a3, b1, acc[3][1]);
            acc[3][2] = dot4(a3, b2, acc[3][2]); acc[3][3] = dot4(a3, b3, acc[3][3]);
        }
        __syncthreads();
    }
    const float wsc = __uint_as_float(*wmaxbits) / 127.0f;
    if constexpr (EPI == 1) {
        const float sc = S_U * wsc;
        float* O = (float*)out0;
        const int j0 = n0 + (tx << 2);
        #pragma unroll
        for (int r = 0; r < 4; r++) {
            const int m = m0 + (ty << 2) + r;
            if (j0 + 3 < N) {
                float4 v;
                v.x = (float)acc[r][0] * sc; v.y = (float)acc[r][1] * sc;
                v.z = (float)acc[r][2] * sc; v.w = (float)acc[r][3] * sc;
                *(float4*)(O + (size_t)m * N + j0) = v;
            } else {
                for (int c = 0; c < 4; c++)
                    if (j0 + c < N) O[(size_t)m * N + j0 + c] = (float)acc[r][c] * sc;
            }
        }
    }
}

// ---------------- MFMA int8 GEMM v2: LDS-staged, 128x128 tile, BK=64 ----------------
// LDS layout per operand: 8 subtiles of (16 rows); subtile st, chunk kc(0..3), row r:
//   byte addr = st*1024 + kc*256 + r*16   (K-major within subtile -> conflict-free b128,
//   and staging lanes r,r+16,r+32,r+48 cover 4 quarters of one 64B line -> coalesced)
// mfma_i32_16x16x64_i8: lane l holds 16B of row (l&15) at k-chunk (l>>4)*16. C/D layout
// as verified: col = lane&15, row = (lane>>4)*4 + reg.
template<int EPI>
__global__ __launch_bounds__(256)
void k_mgemm(const i8* __restrict__ A, const i8* __restrict__ Bw,
             int M, int N, int K,
             const unsigned* __restrict__ wmaxbits,
             void* __restrict__ out0, void* __restrict__ out1) {
    __shared__ i8 sA[8192];
    __shared__ i8 sB[8192];
    const int tid = threadIdx.x;
    const int w = tid >> 6;
    const int l = tid & 63;
    const int m0 = blockIdx.y << 7;
    const int n0 = blockIdx.x << 7;
    const int lr = l & 15;          // row within subtile (stage & read)
    const int lk = l >> 4;          // 16B k-chunk (stage & read)
    // staging source pointers: issue j stages subtile st = j*4 + w
    const i8* gA0 = A  + (size_t)(m0 + (w * 16) + lr) * K + lk * 16;
    const i8* gA1 = A  + (size_t)(m0 + ((4 + w) * 16) + lr) * K + lk * 16;
    const i8* gB0 = Bw + (size_t)(n0 + (w * 16) + lr) * K + lk * 16;
    const i8* gB1 = Bw + (size_t)(n0 + ((4 + w) * 16) + lr) * K + lk * 16;
    i8* lA0 = sA + (w * 1024);
    i8* lA1 = sA + ((4 + w) * 1024);
    i8* lB0 = sB + (w * 1024);
    i8* lB1 = sB + ((4 + w) * 1024);
    // compute-side subtile bases: wave quadrant (w>>1) rows, (w&1) cols
    const int mw = (w >> 1) * 4;    // A subtile base
    const int nw = (w & 1) * 4;     // B subtile base
    const int rdoff = lk * 256 + lr * 16;
    v4i acc[4][4] = {};
    for (int k0 = 0; k0 < K; k0 += 64) {
        gload16(gA0 + k0, lA0);
        gload16(gA1 + k0, lA1);
        gload16(gB0 + k0, lB0);
        gload16(gB1 + k0, lB1);
        __syncthreads();           // compiler drains vmcnt before barrier
        v4i af[4], bf[4];
        #pragma unroll
        for (int t = 0; t < 4; t++) {
            af[t] = *(const v4i*)(sA + (mw + t) * 1024 + rdoff);
            bf[t] = *(const v4i*)(sB + (nw + t) * 1024 + rdoff);
        }
        #pragma unroll
        for (int mt = 0; mt < 4; mt++)
            #pragma unroll
            for (int nt = 0; nt < 4; nt++)
                acc[mt][nt] = __builtin_amdgcn_mfma_i32_16x16x64_i8(af[mt], bf[nt], acc[mt][nt], 0, 0, 0);
        __syncthreads();
    }
    const float wsc = __uint_as_float(*wmaxbits) / 127.0f;
    const int m0w = m0 + (w >> 1) * 64;
    const int n0w = n0 + (w & 1) * 64;
    if constexpr (EPI == 0 || EPI == 2) {
        const float sc = (EPI == 0 ? S_IN : S_DTLN) * wsc;
        const float qs = (EPI == 0 ? S_Z : S_DT);
        const int b = m0w >> 11;
        #pragma unroll
        for (int nt = 0; nt < 4; nt++) {
            const int j = n0w + nt * 16 + lr;
            i8* dst;
            if constexpr (EPI == 0) dst = (j < 4096) ? (i8*)out0 : (i8*)out1;
            else dst = (i8*)out0;
            const int jj = j & 4095;
            #pragma unroll
            for (int mt = 0; mt < 4; mt++) {
                const int sbase = (m0w & 2047) + mt * 16 + lk * 4;
                unsigned pk = 0;
                #pragma unroll
                for (int r = 0; r < 4; r++) {
                    float v = (float)acc[mt][nt][r] * sc;
                    pk |= ((unsigned)(q8i(v, qs) & 255)) << (8 * r);
                }
                *(unsigned*)(dst + ((size_t)b * 4096 + jj) * 2048 + sbase) = pk;
            }
        }
    } else {
        const float sc = S_Y * wsc;
        float* O = (float*)out0;
        #pragma unroll
        for (int mt = 0; mt < 4; mt++)
            #pragma unroll
            for (int r = 0; r < 4; r++) {
                const int m = m0w + mt * 16 + lk * 4 + r;
                #pragma unroll
                for (int nt = 0; nt < 4; nt++)
                    O[(size_t)m * N + n0w + nt * 16 + lr] = (float)acc[mt][nt][r] * sc;
            }
    }
}

// ---------------- depthwise causal conv(K=4) + silu + quant ----------------
__global__ __launch_bounds__(256)
void k_conv(const i8* __restrict__ hsq, const i8* __restrict__ cwq,
            const float* __restrict__ conv_b, const unsigned* __restrict__ cmaxbits,
            i8* __restrict__ uq, i8* __restrict__ uqT) {
    __shared__ char lt[64][68];
    const int tid = threadIdx.x;
    const int b = blockIdx.z;
    const int d0 = blockIdx.y << 6;
    const int s0 = blockIdx.x << 6;
    const int dl = tid >> 2;
    const int sg = tid & 3;
    const int d = d0 + dl;
    const int sbase = s0 + (sg << 4);
    const i8* xp = hsq + ((size_t)b * 4096 + d) * 2048;
    int v[19];
    #pragma unroll
    for (int i = 0; i < 19; i++) {
        int s = sbase - 3 + i;
        v[i] = (s >= 0) ? (int)xp[s] : 0;
    }
    const unsigned cw = *(const unsigned*)(cwq + (size_t)d * 4);
    const int w0 = (int)(char)(cw & 255);
    const int w1 = (int)(char)((cw >> 8) & 255);
    const int w2 = (int)(char)((cw >> 16) & 255);
    const int w3 = (int)(char)((cw >> 24) & 255);
    const float cws = __uint_as_float(*cmaxbits) / 127.0f;
    const float sc = S_Z * cws;
    const float bias = conv_b[d];
    unsigned pk[4] = {0, 0, 0, 0};
    #pragma unroll
    for (int t = 0; t < 16; t++) {
        int acc = v[t] * w0 + v[t + 1] * w1 + v[t + 2] * w2 + v[t + 3] * w3;
        float f = __fadd_rn(__fmul_rn((float)acc, sc), bias);
        float sig = 1.0f / (1.0f + expf(-f));
        float sl = __fmul_rn(f, sig);
        int q = q8i(sl, S_U);
        pk[t >> 2] |= ((unsigned)(q & 255)) << ((t & 3) * 8);
        lt[(sg << 4) + t][dl] = (char)q;
    }
    *(int4*)(uq + ((size_t)b * 4096 + d) * 2048 + sbase) = make_int4(pk[0], pk[1], pk[2], pk[3]);
    __syncthreads();
    const int rr = tid >> 2;
    const int wg = tid & 3;
    const int* rp = (const int*)(&lt[rr][wg << 4]);
    int4 o; o.x = rp[0]; o.y = rp[1]; o.z = rp[2]; o.w = rp[3];
    *(int4*)(uqT + ((size_t)b * 2048 + s0 + rr) * 4096 + d0 + (wg << 4)) = o;
}

// ---------------- rmsnorm + quant; B/C written TRANSPOSED [b][n][s] ----------------
__global__ __launch_bounds__(64)
void k_rms(const float* __restrict__ p,
           const float* __restrict__ wdt, const float* __restrict__ wB, const float* __restrict__ wC,
           i8* __restrict__ dtq, i8* __restrict__ bqT, i8* __restrict__ cqT) {
    const int row = blockIdx.x;
    const int lane = threadIdx.x;
    const float* x = p + (size_t)row * 160;
    float a0 = x[lane], a1 = x[64 + lane];
    float bb = (lane < 16) ? x[128 + lane] : 0.0f;
    float cc = (lane < 16) ? x[144 + lane] : 0.0f;
    float sdt = __fadd_rn(__fmul_rn(a0, a0), __fmul_rn(a1, a1));
    float sB = __fmul_rn(bb, bb);
    float sC = __fmul_rn(cc, cc);
    #pragma unroll
    for (int off = 32; off; off >>= 1) {
        sdt = __fadd_rn(sdt, __shfl_xor(sdt, off));
        sB  = __fadd_rn(sB,  __shfl_xor(sB, off));
        sC  = __fadd_rn(sC,  __shfl_xor(sC, off));
    }
    float rdt = 1.0f / sqrtf(sdt / 128.0f + 1e-6f);
    float rB  = 1.0f / sqrtf(sB / 16.0f + 1e-6f);
    float rC  = 1.0f / sqrtf(sC / 16.0f + 1e-6f);
    dtq[(size_t)row * 128 + lane]      = (i8)q8i(__fmul_rn(wdt[lane],      __fmul_rn(a0, rdt)), S_DTLN);
    dtq[(size_t)row * 128 + 64 + lane] = (i8)q8i(__fmul_rn(wdt[64 + lane], __fmul_rn(a1, rdt)), S_DTLN);
    if (lane < 16) {
        size_t tpos = ((size_t)(row >> 11) * 16 + lane) * 2048 + (row & 2047);
        bqT[tpos] = (i8)q8i(__fmul_rn(wB[lane], __fmul_rn(bb, rB)), S_B);
        cqT[tpos] = (i8)q8i(__fmul_rn(wC[lane], __fmul_rn(cc, rC)), S_C);
    }
}

// ---------------- LUT builders (bit-identical op sequences) ----------------
__global__ __launch_bounds__(256)
void k_lut_dt(const float* __restrict__ dt_bias, float* __restrict__ lut) {
    const int d = blockIdx.x;
    const int q = threadIdx.x;
    const float bias = dt_bias[d];
    lut[(size_t)d * 256 + q] =
        softplus_f(__fadd_rn(__fmul_rn((float)(q - 128), S_DT), bias));
}
__global__ __launch_bounds__(256)
void k_lut_silu(float* __restrict__ lut) {
    const int q = threadIdx.x;
    float gv = __fmul_rn((float)(q - 128), S_Z);
    float sg = __fmul_rn(gv, 1.0f / (1.0f + expf(-gv)));
    lut[q] = sg;
}

// ---------------- scan v3: 16-step tiles, vector loads, batched LUT/expf ----------------
__global__ __launch_bounds__(256)
void k_scan3(const i8* __restrict__ dt8, const i8* __restrict__ uq, const i8* __restrict__ gq,
             const i8* __restrict__ BqT, const i8* __restrict__ CqT,
             const float* __restrict__ lut_dt, const float* __restrict__ lut_silu,
             const float* __restrict__ A_log, const float* __restrict__ D_skip,
             i8* __restrict__ yq) {
    const int g = blockIdx.x * 256 + threadIdx.x;
    const int n = g & 15;
    const int bd = g >> 4;
    const int d = bd & 4095;
    const int b = bd >> 12;
    const float Acoef = -expf(A_log[(size_t)d * 16 + n]);
    const float Dd = D_skip[d];
    const float* ldt = lut_dt + (size_t)d * 256;
    const v4i* dtp = (const v4i*)(dt8 + (size_t)bd * 2048);
    const v4i* up  = (const v4i*)(uq  + (size_t)bd * 2048);
    const v4i* gp  = (const v4i*)(gq  + (size_t)bd * 2048);
    const v4i* Bp  = (const v4i*)(BqT + ((size_t)b * 16 + n) * 2048);
    const v4i* Cp  = (const v4i*)(CqT + ((size_t)b * 16 + n) * 2048);
    i8* yp = yq + (size_t)b * 2048 * 4096 + d;
    float h = 0.0f;
    v4i dtw = dtp[0], uw = up[0], gw = gp[0], bw = Bp[0], cw = Cp[0];
    for (int t = 0; t < 128; t++) {
        v4i ndt, nu, ng, nb, nc;
        if (t < 127) { ndt = dtp[t + 1]; nu = up[t + 1]; ng = gp[t + 1]; nb = Bp[t + 1]; nc = Cp[t + 1]; }
        float dtv[16], dA[16];
        #pragma unroll
        for (int j = 0; j < 16; j++)
            dtv[j] = ldt[sbyte_of(dtw[j >> 2], j & 3) + 128];
        #pragma unroll
        for (int j = 0; j < 16; j++)
            dA[j] = expf(__fmul_rn(dtv[j], Acoef));
        float ysave = 0.0f;
        #pragma unroll
        for (int j = 0; j < 16; j++) {
            float uv = __fmul_rn((float)sbyte_of(uw[j >> 2], j & 3), S_U);
            float Bv = __fmul_rn((float)sbyte_of(bw[j >> 2], j & 3), S_B);
            float Cv = __fmul_rn((float)sbyte_of(cw[j >> 2], j & 3), S_C);
            h = __fadd_rn(__fmul_rn(h, dA[j]), __fmul_rn(__fmul_rn(dtv[j], uv), Bv));
            float y = __fmul_rn(h, Cv);
            y = __fadd_rn(y, __shfl_xor(y, 1));
            y = __fadd_rn(y, __shfl_xor(y, 2));
            y = __fadd_rn(y, __shfl_xor(y, 4));
            y = __fadd_rn(y, __shfl_xor(y, 8));
            if (j == n) ysave = y;
        }
        int uws = (n & 8) ? ((n & 4) ? uw[3] : uw[2]) : ((n & 4) ? uw[1] : uw[0]);
        int gws = (n & 8) ? ((n & 4) ? gw[3] : gw[2]) : ((n & 4) ? gw[1] : gw[0]);
        float uvn = __fmul_rn((float)(int)(signed char)((unsigned)uws >> ((n & 3) * 8)), S_U);
        int gb = (int)(signed char)((unsigned)gws >> ((n & 3) * 8));
        float ys = __fadd_rn(ysave, __fmul_rn(uvn, Dd));
        float sg = lut_silu[gb + 128];
        float vv = __fmul_rn(ys, sg);
        yp[(size_t)(t * 16 + n) * 4096] = (i8)q8i(vv, S_Y);
        if (t < 127) { dtw = ndt; uw = nu; gw = ng; bw = nb; cw = nc; }
    }
}

extern "C" void kernel_launch(void* const* d_in, const int* in_sizes, int n_in,
                              void* d_out, int out_size, void* d_ws, size_t ws_size,
                              hipStream_t stream) {
    const float* hidden   = (const float*)d_in[0];
    const float* in_proj  = (const float*)d_in[1];
    const float* conv_w   = (const float*)d_in[2];
    const float* conv_b   = (const float*)d_in[3];
    const float* x_proj   = (const float*)d_in[4];
    const float* dt_ln    = (const float*)d_in[5];
    const float* B_ln     = (const float*)d_in[6];
    const float* C_ln     = (const float*)d_in[7];
    const float* dt_proj  = (const float*)d_in[8];
    const float* dt_bias  = (const float*)d_in[9];
    const float* A_log    = (const float*)d_in[10];
    const float* D_skip   = (const float*)d_in[11];
    const float* out_proj = (const float*)d_in[12];
    float* out = (float*)d_out;

    // ---- workspace layout, 46,416,128 B (proven footprint) ----
    char* ws = (char*)d_ws;
    unsigned* scales = (unsigned*)ws;                       // 256 B
    i8* WQ   = (i8*)(ws + 256);                             // 16,777,216: in_proj q8 -> u_qT -> y_q
    i8* XQ   = (i8*)(ws + 16777472);                        //  8,388,608: x_q -> OWQ
    i8* HSQ  = (i8*)(ws + 25166080);                        // 16,777,216: hs_q -> dt8
    char* S0 = ws + 41943296;
    float* SSMP = (float*)S0;                               // 2,621,440: ssm_p
    i8* DTQb = (i8*)(S0 + 2621440);                         //   524,288: dt_q
    i8* XWQ  = (i8*)(S0 + 3145728);                         //   655,360
    i8* DWQ  = (i8*)(S0 + 3801088);                         //   524,288
    i8* CWQ  = (i8*)(S0 + 4325376);                         //    16,384
    float* LUTDT = (float*)S0;                              // 4,194,304 (built after GEMM3)
    float* LUTSI = (float*)(S0 + 4194304);                  //     1,024
    i8* BQT  = (i8*)(S0 + 4341760);                         //    65,536: B_q^T [2][16][2048]
    i8* CQT  = (i8*)(S0 + 4407296);                         //    65,536: C_q^T

    i8* GQ = (i8*)d_out;                                    // gate_q [2][4096][2048]
    i8* UQ = (i8*)d_out + 16777216;                         // u_q    [2][4096][2048]
    i8* UQT = WQ;                                           // u_qT [2][2048][4096]
    i8* OWQ = XQ;                                           // out_proj q8
    i8* DT8 = HSQ;                                          // dt8 [2][4096][2048]
    i8* YQ  = WQ;                                           // y_q [2][2048][4096]

    hipMemsetAsync(scales, 0, 256, stream);

    k_maxabs<<<2048, 256, 0, stream>>>(in_proj, 16777216LL, scales + 0);
    k_maxabs<<<64,   256, 0, stream>>>(conv_w,  16384LL,    scales + 1);
    k_maxabs<<<512,  256, 0, stream>>>(x_proj,  655360LL,   scales + 2);
    k_maxabs<<<512,  256, 0, stream>>>(dt_proj, 524288LL,   scales + 3);
    k_maxabs<<<1024, 256, 0, stream>>>(out_proj, 8388608LL, scales + 4);

    k_quant_w<<<16384, 256, 0, stream>>>(in_proj, 16777216LL, scales + 0, WQ);
    k_quant_w<<<16,    256, 0, stream>>>(conv_w,  16384LL,    scales + 1, CWQ);
    k_quant_w<<<640,   256, 0, stream>>>(x_proj,  655360LL,   scales + 2, XWQ);
    k_quant_w<<<512,   256, 0, stream>>>(dt_proj, 524288LL,   scales + 3, DWQ);
    k_quant_x<<<8192,  256, 0, stream>>>(hidden,  8388608LL,  S_IN, XQ);

    // GEMM1 (MFMA/LDS): proj -> hs_q(HSQ) / gate_q(GQ), int8 [b,d,s]
    k_mgemm<0><<<dim3(64, 32), 256, 0, stream>>>(XQ, WQ, 4096, 8192, 2048, scales + 0, HSQ, GQ);

    k_quant_w<<<8192, 256, 0, stream>>>(out_proj, 8388608LL, scales + 4, OWQ);

    dim3 gc(32, 64, 2);
    k_conv<<<gc, 256, 0, stream>>>(HSQ, CWQ, conv_b, scales + 1, UQ, UQT);

    // GEMM2 (dot4, N=160): ssm_p
    dim3 g2(3, 64);
    k_gemm<1><<<g2, 256, 0, stream>>>(UQT, XWQ, 4096, 160, 4096, scales + 2, SSMP, nullptr);

    k_rms<<<4096, 64, 0, stream>>>(SSMP, dt_ln, B_ln, C_ln, DTQb, BQT, CQT);

    // GEMM3 (MFMA/LDS): dt8 -> [b,d,s] into HSQ
    k_mgemm<2><<<dim3(32, 32), 256, 0, stream>>>(DTQb, DWQ, 4096, 4096, 128, scales + 3, DT8, nullptr);

    k_lut_dt<<<4096, 256, 0, stream>>>(dt_bias, LUTDT);
    k_lut_silu<<<1, 256, 0, stream>>>(LUTSI);

    k_scan3<<<512, 256, 0, stream>>>(DT8, UQ, GQ, BQT, CQT, LUTDT, LUTSI, A_log, D_skip, YQ);

    // GEMM4 (MFMA/LDS): out = y_q @ out_proj^T -> f32
    k_mgemm<3><<<dim3(16, 32), 256, 0, stream>>>(YQ, OWQ, 4096, 2048, 4096, scales + 4, out, nullptr);
}

// Round 8
// 717.937 us; speedup vs baseline: 4.3722x; 1.0973x over previous
//
#include <hip/hip_runtime.h>
#include <stdint.h>

typedef signed char i8;
typedef int v4i __attribute__((ext_vector_type(4)));

#define S_IN  0.05f
#define S_Z   0.02f
#define S_U   0.01f
#define S_DTLN 0.02f
#define S_B   0.02f
#define S_C   0.02f
#define S_DT  0.01f
#define S_Y   0.01f

// qa(): round-half-even (matches jnp.round), clip to [-128,127]
__device__ __forceinline__ float q8f(float x, float s) {
    float r = rintf(x / s);
    return fmaxf(-128.0f, fminf(127.0f, r));
}
__device__ __forceinline__ int q8i(float x, float s) { return (int)q8f(x, s); }

__device__ __forceinline__ float softplus_f(float x) {
    return __fadd_rn(fmaxf(x, 0.0f), log1pf(expf(-fabsf(x))));
}

__device__ __forceinline__ int sbyte_of(int w, int j) {
    return (int)(signed char)((unsigned)w >> (j * 8));
}

// async global->LDS, 16B per lane; LDS dest = base + lane*16 (wave-uniform base)
__device__ __forceinline__ void gload16(const i8* g, i8* lds) {
    __builtin_amdgcn_global_load_lds(
        (const __attribute__((address_space(1))) unsigned int*)g,
        (__attribute__((address_space(3))) unsigned int*)lds,
        16, 0, 0);
}

// ---------------- max|w| reduction ----------------
__global__ __launch_bounds__(256)
void k_maxabs(const float* __restrict__ w, long long n, unsigned* __restrict__ out) {
    unsigned m = 0;
    long long stride = (long long)gridDim.x * 256;
    for (long long i = (long long)blockIdx.x * 256 + threadIdx.x; i < n; i += stride)
        m = max(m, __float_as_uint(fabsf(w[i])));
    #pragma unroll
    for (int off = 32; off; off >>= 1) {
        unsigned o = (unsigned)__shfl_xor((int)m, off);
        m = max(m, o);
    }
    __shared__ unsigned sm[4];
    if ((threadIdx.x & 63) == 0) sm[threadIdx.x >> 6] = m;
    __syncthreads();
    if (threadIdx.x == 0) {
        unsigned r = max(max(sm[0], sm[1]), max(sm[2], sm[3]));
        atomicMax(out, r);
    }
}

// ---------------- weight quant ----------------
__global__ __launch_bounds__(256)
void k_quant_w(const float* __restrict__ w, long long n,
               const unsigned* __restrict__ maxbits, i8* __restrict__ o) {
    long long i = ((long long)blockIdx.x * 256 + threadIdx.x) * 4;
    if (i >= n) return;
    float s = __uint_as_float(*maxbits) / 127.0f;
    float4 v = *(const float4*)(w + i);
    unsigned pk = ((unsigned)(q8i(v.x, s) & 255))
                | ((unsigned)(q8i(v.y, s) & 255) << 8)
                | ((unsigned)(q8i(v.z, s) & 255) << 16)
                | ((unsigned)(q8i(v.w, s) & 255) << 24);
    *(unsigned*)(o + i) = pk;
}

// ---------------- activation quant ----------------
__global__ __launch_bounds__(256)
void k_quant_x(const float* __restrict__ x, long long n, float s, i8* __restrict__ o) {
    long long i = ((long long)blockIdx.x * 256 + threadIdx.x) * 4;
    if (i >= n) return;
    float4 v = *(const float4*)(x + i);
    unsigned pk = ((unsigned)(q8i(v.x, s) & 255))
                | ((unsigned)(q8i(v.y, s) & 255) << 8)
                | ((unsigned)(q8i(v.z, s) & 255) << 16)
                | ((unsigned)(q8i(v.w, s) & 255) << 24);
    *(unsigned*)(o + i) = pk;
}

// ---------------- MFMA int8 GEMM: LDS-staged, 128x128 tile, BK=64 ----------------
// LDS: 8 subtiles x (16 rows); byte addr = st*1024 + kc*256 + r*16 (K-major subtile).
// EPI 0: int8 transposed split hs/gate; EPI 1: f32 ssm_p[m][160] guarded; EPI 2: int8
// transposed dt8; EPI 3: f32 out.
template<int EPI>
__global__ __launch_bounds__(256)
void k_mgemm(const i8* __restrict__ A, const i8* __restrict__ Bw,
             int M, int N, int K,
             const unsigned* __restrict__ wmaxbits,
             void* __restrict__ out0, void* __restrict__ out1) {
    __shared__ i8 sA[8192];
    __shared__ i8 sB[8192];
    const int tid = threadIdx.x;
    const int w = tid >> 6;
    const int l = tid & 63;
    const int m0 = blockIdx.y << 7;
    const int n0 = blockIdx.x << 7;
    const int lr = l & 15;
    const int lk = l >> 4;
    const i8* gA0 = A  + (size_t)(m0 + (w * 16) + lr) * K + lk * 16;
    const i8* gA1 = A  + (size_t)(m0 + ((4 + w) * 16) + lr) * K + lk * 16;
    const i8* gB0 = Bw + (size_t)(n0 + (w * 16) + lr) * K + lk * 16;
    const i8* gB1 = Bw + (size_t)(n0 + ((4 + w) * 16) + lr) * K + lk * 16;
    i8* lA0 = sA + (w * 1024);
    i8* lA1 = sA + ((4 + w) * 1024);
    i8* lB0 = sB + (w * 1024);
    i8* lB1 = sB + ((4 + w) * 1024);
    const int mw = (w >> 1) * 4;
    const int nw = (w & 1) * 4;
    const int rdoff = lk * 256 + lr * 16;
    v4i acc[4][4] = {};
    for (int k0 = 0; k0 < K; k0 += 64) {
        gload16(gA0 + k0, lA0);
        gload16(gA1 + k0, lA1);
        gload16(gB0 + k0, lB0);
        gload16(gB1 + k0, lB1);
        __syncthreads();
        v4i af[4], bf[4];
        #pragma unroll
        for (int t = 0; t < 4; t++) {
            af[t] = *(const v4i*)(sA + (mw + t) * 1024 + rdoff);
            bf[t] = *(const v4i*)(sB + (nw + t) * 1024 + rdoff);
        }
        #pragma unroll
        for (int mt = 0; mt < 4; mt++)
            #pragma unroll
            for (int nt = 0; nt < 4; nt++)
                acc[mt][nt] = __builtin_amdgcn_mfma_i32_16x16x64_i8(af[mt], bf[nt], acc[mt][nt], 0, 0, 0);
        __syncthreads();
    }
    const float wsc = __uint_as_float(*wmaxbits) / 127.0f;
    const int m0w = m0 + (w >> 1) * 64;
    const int n0w = n0 + (w & 1) * 64;
    if constexpr (EPI == 0 || EPI == 2) {
        const float sc = (EPI == 0 ? S_IN : S_DTLN) * wsc;
        const float qs = (EPI == 0 ? S_Z : S_DT);
        const int b = m0w >> 11;
        #pragma unroll
        for (int nt = 0; nt < 4; nt++) {
            const int j = n0w + nt * 16 + lr;
            i8* dst;
            if constexpr (EPI == 0) dst = (j < 4096) ? (i8*)out0 : (i8*)out1;
            else dst = (i8*)out0;
            const int jj = j & 4095;
            #pragma unroll
            for (int mt = 0; mt < 4; mt++) {
                const int sbase = (m0w & 2047) + mt * 16 + lk * 4;
                unsigned pk = 0;
                #pragma unroll
                for (int r = 0; r < 4; r++) {
                    float v = (float)acc[mt][nt][r] * sc;
                    pk |= ((unsigned)(q8i(v, qs) & 255)) << (8 * r);
                }
                *(unsigned*)(dst + ((size_t)b * 4096 + jj) * 2048 + sbase) = pk;
            }
        }
    } else if constexpr (EPI == 1) {
        const float sc = S_U * wsc;
        float* O = (float*)out0;
        #pragma unroll
        for (int mt = 0; mt < 4; mt++)
            #pragma unroll
            for (int r = 0; r < 4; r++) {
                const int m = m0w + mt * 16 + lk * 4 + r;
                #pragma unroll
                for (int nt = 0; nt < 4; nt++) {
                    const int j = n0w + nt * 16 + lr;
                    if (j < 160)
                        O[(size_t)m * 160 + j] = (float)acc[mt][nt][r] * sc;
                }
            }
    } else {
        const float sc = S_Y * wsc;
        float* O = (float*)out0;
        #pragma unroll
        for (int mt = 0; mt < 4; mt++)
            #pragma unroll
            for (int r = 0; r < 4; r++) {
                const int m = m0w + mt * 16 + lk * 4 + r;
                #pragma unroll
                for (int nt = 0; nt < 4; nt++)
                    O[(size_t)m * N + n0w + nt * 16 + lr] = (float)acc[mt][nt][r] * sc;
            }
    }
}

// ---------------- depthwise causal conv(K=4) + silu + quant ----------------
__global__ __launch_bounds__(256)
void k_conv(const i8* __restrict__ hsq, const i8* __restrict__ cwq,
            const float* __restrict__ conv_b, const unsigned* __restrict__ cmaxbits,
            i8* __restrict__ uq, i8* __restrict__ uqT) {
    __shared__ char lt[64][68];
    const int tid = threadIdx.x;
    const int b = blockIdx.z;
    const int d0 = blockIdx.y << 6;
    const int s0 = blockIdx.x << 6;
    const int dl = tid >> 2;
    const int sg = tid & 3;
    const int d = d0 + dl;
    const int sbase = s0 + (sg << 4);
    const i8* xp = hsq + ((size_t)b * 4096 + d) * 2048;
    int v[19];
    #pragma unroll
    for (int i = 0; i < 19; i++) {
        int s = sbase - 3 + i;
        v[i] = (s >= 0) ? (int)xp[s] : 0;
    }
    const unsigned cw = *(const unsigned*)(cwq + (size_t)d * 4);
    const int w0 = (int)(char)(cw & 255);
    const int w1 = (int)(char)((cw >> 8) & 255);
    const int w2 = (int)(char)((cw >> 16) & 255);
    const int w3 = (int)(char)((cw >> 24) & 255);
    const float cws = __uint_as_float(*cmaxbits) / 127.0f;
    const float sc = S_Z * cws;
    const float bias = conv_b[d];
    unsigned pk[4] = {0, 0, 0, 0};
    #pragma unroll
    for (int t = 0; t < 16; t++) {
        int acc = v[t] * w0 + v[t + 1] * w1 + v[t + 2] * w2 + v[t + 3] * w3;
        float f = __fadd_rn(__fmul_rn((float)acc, sc), bias);
        float sig = 1.0f / (1.0f + expf(-f));
        float sl = __fmul_rn(f, sig);
        int q = q8i(sl, S_U);
        pk[t >> 2] |= ((unsigned)(q & 255)) << ((t & 3) * 8);
        lt[(sg << 4) + t][dl] = (char)q;
    }
    *(int4*)(uq + ((size_t)b * 4096 + d) * 2048 + sbase) = make_int4(pk[0], pk[1], pk[2], pk[3]);
    __syncthreads();
    const int rr = tid >> 2;
    const int wg = tid & 3;
    const int* rp = (const int*)(&lt[rr][wg << 4]);
    int4 o; o.x = rp[0]; o.y = rp[1]; o.z = rp[2]; o.w = rp[3];
    *(int4*)(uqT + ((size_t)b * 2048 + s0 + rr) * 4096 + d0 + (wg << 4)) = o;
}

// ---------------- rmsnorm + quant; B/C written TRANSPOSED [b][n][s] ----------------
__global__ __launch_bounds__(64)
void k_rms(const float* __restrict__ p,
           const float* __restrict__ wdt, const float* __restrict__ wB, const float* __restrict__ wC,
           i8* __restrict__ dtq, i8* __restrict__ bqT, i8* __restrict__ cqT) {
    const int row = blockIdx.x;
    const int lane = threadIdx.x;
    const float* x = p + (size_t)row * 160;
    float a0 = x[lane], a1 = x[64 + lane];
    float bb = (lane < 16) ? x[128 + lane] : 0.0f;
    float cc = (lane < 16) ? x[144 + lane] : 0.0f;
    float sdt = __fadd_rn(__fmul_rn(a0, a0), __fmul_rn(a1, a1));
    float sB = __fmul_rn(bb, bb);
    float sC = __fmul_rn(cc, cc);
    #pragma unroll
    for (int off = 32; off; off >>= 1) {
        sdt = __fadd_rn(sdt, __shfl_xor(sdt, off));
        sB  = __fadd_rn(sB,  __shfl_xor(sB, off));
        sC  = __fadd_rn(sC,  __shfl_xor(sC, off));
    }
    float rdt = 1.0f / sqrtf(sdt / 128.0f + 1e-6f);
    float rB  = 1.0f / sqrtf(sB / 16.0f + 1e-6f);
    float rC  = 1.0f / sqrtf(sC / 16.0f + 1e-6f);
    dtq[(size_t)row * 128 + lane]      = (i8)q8i(__fmul_rn(wdt[lane],      __fmul_rn(a0, rdt)), S_DTLN);
    dtq[(size_t)row * 128 + 64 + lane] = (i8)q8i(__fmul_rn(wdt[64 + lane], __fmul_rn(a1, rdt)), S_DTLN);
    if (lane < 16) {
        size_t tpos = ((size_t)(row >> 11) * 16 + lane) * 2048 + (row & 2047);
        bqT[tpos] = (i8)q8i(__fmul_rn(wB[lane], __fmul_rn(bb, rB)), S_B);
        cqT[tpos] = (i8)q8i(__fmul_rn(wC[lane], __fmul_rn(cc, rC)), S_C);
    }
}

// ---------------- LUT builders (bit-identical op sequences) ----------------
__global__ __launch_bounds__(256)
void k_lut_dt(const float* __restrict__ dt_bias, float* __restrict__ lut) {
    const int d = blockIdx.x;
    const int q = threadIdx.x;
    const float bias = dt_bias[d];
    lut[(size_t)d * 256 + q] =
        softplus_f(__fadd_rn(__fmul_rn((float)(q - 128), S_DT), bias));
}
__global__ __launch_bounds__(256)
void k_lut_silu(float* __restrict__ lut) {
    const int q = threadIdx.x;
    float gv = __fmul_rn((float)(q - 128), S_Z);
    float sg = __fmul_rn(gv, 1.0f / (1.0f + expf(-gv)));
    lut[q] = sg;
}

// ---------------- scan v4: 16-step tiles + reduce-scatter tree (bit-exact) ----------------
__global__ __launch_bounds__(256)
void k_scan4(const i8* __restrict__ dt8, const i8* __restrict__ uq, const i8* __restrict__ gq,
             const i8* __restrict__ BqT, const i8* __restrict__ CqT,
             const float* __restrict__ lut_dt, const float* __restrict__ lut_silu,
             const float* __restrict__ A_log, const float* __restrict__ D_skip,
             i8* __restrict__ yq) {
    const int g = blockIdx.x * 256 + threadIdx.x;
    const int n = g & 15;
    const int bd = g >> 4;
    const int d = bd & 4095;
    const int b = bd >> 12;
    const float Acoef = -expf(A_log[(size_t)d * 16 + n]);
    const float Dd = D_skip[d];
    const float* ldt = lut_dt + (size_t)d * 256;
    const v4i* dtp = (const v4i*)(dt8 + (size_t)bd * 2048);
    const v4i* up  = (const v4i*)(uq  + (size_t)bd * 2048);
    const v4i* gp  = (const v4i*)(gq  + (size_t)bd * 2048);
    const v4i* Bp  = (const v4i*)(BqT + ((size_t)b * 16 + n) * 2048);
    const v4i* Cp  = (const v4i*)(CqT + ((size_t)b * 16 + n) * 2048);
    i8* yp = yq + (size_t)b * 2048 * 4096 + d;
    float h = 0.0f;
    v4i dtw = dtp[0], uw = up[0], gw = gp[0], bw = Bp[0], cw = Cp[0];
    for (int t = 0; t < 128; t++) {
        v4i ndt, nu, ng, nb, nc;
        if (t < 127) { ndt = dtp[t + 1]; nu = up[t + 1]; ng = gp[t + 1]; nb = Bp[t + 1]; nc = Cp[t + 1]; }
        float dtv[16], dA[16], pj[16], Cv[16], y[16];
        #pragma unroll
        for (int j = 0; j < 16; j++)
            dtv[j] = ldt[sbyte_of(dtw[j >> 2], j & 3) + 128];
        #pragma unroll
        for (int j = 0; j < 16; j++)
            dA[j] = expf(__fmul_rn(dtv[j], Acoef));
        #pragma unroll
        for (int j = 0; j < 16; j++) {
            float uv = __fmul_rn((float)sbyte_of(uw[j >> 2], j & 3), S_U);
            float Bv = __fmul_rn((float)sbyte_of(bw[j >> 2], j & 3), S_B);
            Cv[j] = __fmul_rn((float)sbyte_of(cw[j >> 2], j & 3), S_C);
            pj[j] = __fmul_rn(__fmul_rn(dtv[j], uv), Bv);
        }
        #pragma unroll
        for (int j = 0; j < 16; j++) {
            h = __fadd_rn(__fmul_rn(h, dA[j]), pj[j]);
            y[j] = __fmul_rn(h, Cv[j]);
        }
        // reduce-scatter: same pairwise tree as the xor-1/2/4/8 butterfly (bit-exact);
        // lane n ends with the full 16-lane sum for step (t*16 + n).
        float w8[8];
        #pragma unroll
        for (int i = 0; i < 8; i++) {
            float a = y[2 * i], bq = y[2 * i + 1];
            float snd = (n & 1) ? a : bq;
            float rcv = __shfl_xor(snd, 1);
            float kept = (n & 1) ? bq : a;
            w8[i] = __fadd_rn(kept, rcv);
        }
        float w4[4];
        #pragma unroll
        for (int i = 0; i < 4; i++) {
            float a = w8[2 * i], bq = w8[2 * i + 1];
            float snd = (n & 2) ? a : bq;
            float rcv = __shfl_xor(snd, 2);
            float kept = (n & 2) ? bq : a;
            w4[i] = __fadd_rn(kept, rcv);
        }
        float w2[2];
        #pragma unroll
        for (int i = 0; i < 2; i++) {
            float a = w4[2 * i], bq = w4[2 * i + 1];
            float snd = (n & 4) ? a : bq;
            float rcv = __shfl_xor(snd, 4);
            float kept = (n & 4) ? bq : a;
            w2[i] = __fadd_rn(kept, rcv);
        }
        float ysave;
        {
            float a = w2[0], bq = w2[1];
            float snd = (n & 8) ? a : bq;
            float rcv = __shfl_xor(snd, 8);
            float kept = (n & 8) ? bq : a;
            ysave = __fadd_rn(kept, rcv);
        }
        // epilogue: lane n handles s = t*16 + n
        int uws = (n & 8) ? ((n & 4) ? uw[3] : uw[2]) : ((n & 4) ? uw[1] : uw[0]);
        int gws = (n & 8) ? ((n & 4) ? gw[3] : gw[2]) : ((n & 4) ? gw[1] : gw[0]);
        float uvn = __fmul_rn((float)(int)(signed char)((unsigned)uws >> ((n & 3) * 8)), S_U);
        int gb = (int)(signed char)((unsigned)gws >> ((n & 3) * 8));
        float ys = __fadd_rn(ysave, __fmul_rn(uvn, Dd));
        float sg = lut_silu[gb + 128];
        float vv = __fmul_rn(ys, sg);
        yp[(size_t)(t * 16 + n) * 4096] = (i8)q8i(vv, S_Y);
        if (t < 127) { dtw = ndt; uw = nu; gw = ng; bw = nb; cw = nc; }
    }
}

extern "C" void kernel_launch(void* const* d_in, const int* in_sizes, int n_in,
                              void* d_out, int out_size, void* d_ws, size_t ws_size,
                              hipStream_t stream) {
    const float* hidden   = (const float*)d_in[0];
    const float* in_proj  = (const float*)d_in[1];
    const float* conv_w   = (const float*)d_in[2];
    const float* conv_b   = (const float*)d_in[3];
    const float* x_proj   = (const float*)d_in[4];
    const float* dt_ln    = (const float*)d_in[5];
    const float* B_ln     = (const float*)d_in[6];
    const float* C_ln     = (const float*)d_in[7];
    const float* dt_proj  = (const float*)d_in[8];
    const float* dt_bias  = (const float*)d_in[9];
    const float* A_log    = (const float*)d_in[10];
    const float* D_skip   = (const float*)d_in[11];
    const float* out_proj = (const float*)d_in[12];
    float* out = (float*)d_out;

    // ---- workspace layout, 46,810,368 B high-water ----
    char* ws = (char*)d_ws;
    unsigned* scales = (unsigned*)ws;                       // 256 B
    i8* WQ   = (i8*)(ws + 256);                             // 16,777,216: in_proj q8 -> u_qT -> y_q
    i8* XQ   = (i8*)(ws + 16777472);                        //  8,388,608: x_q -> OWQ
    i8* HSQ  = (i8*)(ws + 25166080);                        // 16,777,216: hs_q -> dt8
    char* S0 = ws + 41943296;
    float* SSMP = (float*)S0;                               // 2,621,440: ssm_p [4096][160]
    i8* XWQp = (i8*)(S0 + 2621440);                         // 1,048,576: x_proj q8 padded [256][4096]
    i8* DTQb = (i8*)(S0 + 3670016);                         //   524,288: dt_q [4096][128]
    i8* DWQ  = (i8*)(S0 + 4194304);                         //   524,288: dt_proj q8
    i8* CWQ  = (i8*)(S0 + 4718592);                         //    16,384: conv q8
    float* LUTSI = (float*)(S0 + 4734976);                  //     1,024
    i8* BQT  = (i8*)(S0 + 4736000);                         //    65,536: B_q^T [2][16][2048]
    i8* CQT  = (i8*)(S0 + 4801536);                         //    65,536: C_q^T
    // LUTDT (4 MB) overlays SSMP+XWQp+DTQb-head; all three dead once it is built
    float* LUTDT = (float*)S0;

    i8* GQ = (i8*)d_out;                                    // gate_q [2][4096][2048]
    i8* UQ = (i8*)d_out + 16777216;                         // u_q    [2][4096][2048]
    i8* UQT = WQ;                                           // u_qT [2][2048][4096]
    i8* OWQ = XQ;                                           // out_proj q8
    i8* DT8 = HSQ;                                          // dt8 [2][4096][2048]
    i8* YQ  = WQ;                                           // y_q [2][2048][4096]

    hipMemsetAsync(scales, 0, 256, stream);
    hipMemsetAsync(XWQp, 0, 1048576, stream);               // zero pad rows 160..255

    k_maxabs<<<2048, 256, 0, stream>>>(in_proj, 16777216LL, scales + 0);
    k_maxabs<<<64,   256, 0, stream>>>(conv_w,  16384LL,    scales + 1);
    k_maxabs<<<512,  256, 0, stream>>>(x_proj,  655360LL,   scales + 2);
    k_maxabs<<<512,  256, 0, stream>>>(dt_proj, 524288LL,   scales + 3);
    k_maxabs<<<1024, 256, 0, stream>>>(out_proj, 8388608LL, scales + 4);

    k_quant_w<<<16384, 256, 0, stream>>>(in_proj, 16777216LL, scales + 0, WQ);
    k_quant_w<<<16,    256, 0, stream>>>(conv_w,  16384LL,    scales + 1, CWQ);
    k_quant_w<<<640,   256, 0, stream>>>(x_proj,  655360LL,   scales + 2, XWQp);
    k_quant_w<<<512,   256, 0, stream>>>(dt_proj, 524288LL,   scales + 3, DWQ);
    k_quant_x<<<8192,  256, 0, stream>>>(hidden,  8388608LL,  S_IN, XQ);

    // GEMM1 (MFMA): proj -> hs_q(HSQ) / gate_q(GQ), int8 [b,d,s]
    k_mgemm<0><<<dim3(64, 32), 256, 0, stream>>>(XQ, WQ, 4096, 8192, 2048, scales + 0, HSQ, GQ);

    k_quant_w<<<8192, 256, 0, stream>>>(out_proj, 8388608LL, scales + 4, OWQ);

    dim3 gc(32, 64, 2);
    k_conv<<<gc, 256, 0, stream>>>(HSQ, CWQ, conv_b, scales + 1, UQ, UQT);

    // GEMM2 (MFMA, zero-padded B to 256 rows, stores guarded to j<160): ssm_p
    k_mgemm<1><<<dim3(2, 32), 256, 0, stream>>>(UQT, XWQp, 4096, 256, 4096, scales + 2, SSMP, nullptr);

    k_rms<<<4096, 64, 0, stream>>>(SSMP, dt_ln, B_ln, C_ln, DTQb, BQT, CQT);

    // GEMM3 (MFMA): dt8 -> [b,d,s] into HSQ
    k_mgemm<2><<<dim3(32, 32), 256, 0, stream>>>(DTQb, DWQ, 4096, 4096, 128, scales + 3, DT8, nullptr);

    k_lut_dt<<<4096, 256, 0, stream>>>(dt_bias, LUTDT);
    k_lut_silu<<<1, 256, 0, stream>>>(LUTSI);

    k_scan4<<<512, 256, 0, stream>>>(DT8, UQ, GQ, BQT, CQT, LUTDT, LUTSI, A_log, D_skip, YQ);

    // GEMM4 (MFMA): out = y_q @ out_proj^T -> f32
    k_mgemm<3><<<dim3(16, 32), 256, 0, stream>>>(YQ, OWQ, 4096, 2048, 4096, scales + 4, out, nullptr);
}

// Round 10
// 702.029 us; speedup vs baseline: 4.4713x; 1.0227x over previous
//
#include <hip/hip_runtime.h>
#include <stdint.h>

typedef signed char i8;
typedef int v4i __attribute__((ext_vector_type(4)));

#define S_IN  0.05f
#define S_Z   0.02f
#define S_U   0.01f
#define S_DTLN 0.02f
#define S_B   0.02f
#define S_C   0.02f
#define S_DT  0.01f
#define S_Y   0.01f

// qa(): round-half-even (matches jnp.round), clip to [-128,127]
__device__ __forceinline__ float q8f(float x, float s) {
    float r = rintf(x / s);
    return fmaxf(-128.0f, fminf(127.0f, r));
}
__device__ __forceinline__ int q8i(float x, float s) { return (int)q8f(x, s); }

__device__ __forceinline__ float softplus_f(float x) {
    return __fadd_rn(fmaxf(x, 0.0f), log1pf(expf(-fabsf(x))));
}

__device__ __forceinline__ int sbyte_of(int w, int j) {
    return (int)(signed char)((unsigned)w >> (j * 8));
}
__device__ __forceinline__ int ubyte_of(int w, int j) {
    return (int)(((unsigned)w >> (j * 8)) & 255u);
}

// async global->LDS, 16B per lane; LDS dest = wave-uniform base + lane*16
__device__ __forceinline__ void gload16(const i8* g, i8* lds) {
    __builtin_amdgcn_global_load_lds(
        (const __attribute__((address_space(1))) unsigned int*)g,
        (__attribute__((address_space(3))) unsigned int*)lds,
        16, 0, 0);
}

// ---------------- max|w| reduction ----------------
__global__ __launch_bounds__(256)
void k_maxabs(const float* __restrict__ w, long long n, unsigned* __restrict__ out) {
    unsigned m = 0;
    long long stride = (long long)gridDim.x * 256;
    for (long long i = (long long)blockIdx.x * 256 + threadIdx.x; i < n; i += stride)
        m = max(m, __float_as_uint(fabsf(w[i])));
    #pragma unroll
    for (int off = 32; off; off >>= 1) {
        unsigned o = (unsigned)__shfl_xor((int)m, off);
        m = max(m, o);
    }
    __shared__ unsigned sm[4];
    if ((threadIdx.x & 63) == 0) sm[threadIdx.x >> 6] = m;
    __syncthreads();
    if (threadIdx.x == 0) {
        unsigned r = max(max(sm[0], sm[1]), max(sm[2], sm[3]));
        atomicMax(out, r);
    }
}

// ---------------- weight quant ----------------
__global__ __launch_bounds__(256)
void k_quant_w(const float* __restrict__ w, long long n,
               const unsigned* __restrict__ maxbits, i8* __restrict__ o) {
    long long i = ((long long)blockIdx.x * 256 + threadIdx.x) * 4;
    if (i >= n) return;
    float s = __uint_as_float(*maxbits) / 127.0f;
    float4 v = *(const float4*)(w + i);
    unsigned pk = ((unsigned)(q8i(v.x, s) & 255))
                | ((unsigned)(q8i(v.y, s) & 255) << 8)
                | ((unsigned)(q8i(v.z, s) & 255) << 16)
                | ((unsigned)(q8i(v.w, s) & 255) << 24);
    *(unsigned*)(o + i) = pk;
}

// ---------------- activation quant ----------------
__global__ __launch_bounds__(256)
void k_quant_x(const float* __restrict__ x, long long n, float s, i8* __restrict__ o) {
    long long i = ((long long)blockIdx.x * 256 + threadIdx.x) * 4;
    if (i >= n) return;
    float4 v = *(const float4*)(x + i);
    unsigned pk = ((unsigned)(q8i(v.x, s) & 255))
                | ((unsigned)(q8i(v.y, s) & 255) << 8)
                | ((unsigned)(q8i(v.z, s) & 255) << 16)
                | ((unsigned)(q8i(v.w, s) & 255) << 24);
    *(unsigned*)(o + i) = pk;
}

// ---------------- MFMA int8 GEMM: LDS-staged, 128x128 tile, BK=128 bytes ----------------
// LDS per operand: 8 subtiles x 16 rows x 128B = 16KB; byte = st*2048 + kc*256 + r*16.
// Per K-step: 32 gload16 issues/block, 2 barriers, 32 MFMA/wave (2 k64-groups x 16).
// Grids must have nwg % 8 == 0 (bijective XCD swizzle).
template<int EPI>
__global__ __launch_bounds__(256)
void k_mgemm(const i8* __restrict__ A, const i8* __restrict__ Bw,
             int M, int N, int K,
             const unsigned* __restrict__ wmaxbits,
             void* __restrict__ out0, void* __restrict__ out1) {
    __shared__ i8 sA[16384];
    __shared__ i8 sB[16384];
    const int tid = threadIdx.x;
    const int w = tid >> 6;
    const int l = tid & 63;
    // bijective XCD swizzle over linearized grid (nwg % 8 == 0 for all our grids)
    int id = blockIdx.y * gridDim.x + blockIdx.x;
    const int qq = (gridDim.x * gridDim.y) >> 3;
    id = (id & 7) * qq + (id >> 3);
    const int m0 = (id / gridDim.x) << 7;
    const int n0 = (id % gridDim.x) << 7;
    const int lr = l & 15;
    const int lk = l >> 4;
    const i8* gA = A  + (size_t)(m0 + lr) * K + lk * 16;
    const i8* gB = Bw + (size_t)(n0 + lr) * K + lk * 16;
    const size_t rowK16 = (size_t)16 * K;
    const int mw = (w >> 1) * 4;
    const int nw = (w & 1) * 4;
    const int rdoff = lk * 256 + lr * 16;
    v4i acc[4][4] = {};
    for (int k0 = 0; k0 < K; k0 += 128) {
        // stage: wave w handles subtiles w and w+4 of both operands, 2 halves each
        gload16(gA + rowK16 * w + k0,            sA + w * 2048);
        gload16(gA + rowK16 * w + k0 + 64,       sA + w * 2048 + 1024);
        gload16(gA + rowK16 * (4 + w) + k0,      sA + (4 + w) * 2048);
        gload16(gA + rowK16 * (4 + w) + k0 + 64, sA + (4 + w) * 2048 + 1024);
        gload16(gB + rowK16 * w + k0,            sB + w * 2048);
        gload16(gB + rowK16 * w + k0 + 64,       sB + w * 2048 + 1024);
        gload16(gB + rowK16 * (4 + w) + k0,      sB + (4 + w) * 2048);
        gload16(gB + rowK16 * (4 + w) + k0 + 64, sB + (4 + w) * 2048 + 1024);
        __syncthreads();
        #pragma unroll
        for (int k64 = 0; k64 < 2; k64++) {
            v4i af[4], bf[4];
            #pragma unroll
            for (int t = 0; t < 4; t++) {
                af[t] = *(const v4i*)(sA + (mw + t) * 2048 + k64 * 1024 + rdoff);
                bf[t] = *(const v4i*)(sB + (nw + t) * 2048 + k64 * 1024 + rdoff);
            }
            #pragma unroll
            for (int mt = 0; mt < 4; mt++)
                #pragma unroll
                for (int nt = 0; nt < 4; nt++)
                    acc[mt][nt] = __builtin_amdgcn_mfma_i32_16x16x64_i8(af[mt], bf[nt], acc[mt][nt], 0, 0, 0);
        }
        __syncthreads();
    }
    const float wsc = __uint_as_float(*wmaxbits) / 127.0f;
    const int m0w = m0 + (w >> 1) * 64;
    const int n0w = n0 + (w & 1) * 64;
    if constexpr (EPI == 0 || EPI == 2) {
        const float sc = (EPI == 0 ? S_IN : S_DTLN) * wsc;
        const float qs = (EPI == 0 ? S_Z : S_DT);
        const int b = m0w >> 11;
        #pragma unroll
        for (int nt = 0; nt < 4; nt++) {
            const int j = n0w + nt * 16 + lr;
            i8* dst;
            if constexpr (EPI == 0) dst = (j < 4096) ? (i8*)out0 : (i8*)out1;
            else dst = (i8*)out0;
            const int jj = j & 4095;
            #pragma unroll
            for (int mt = 0; mt < 4; mt++) {
                const int sbase = (m0w & 2047) + mt * 16 + lk * 4;
                unsigned pk = 0;
                #pragma unroll
                for (int r = 0; r < 4; r++) {
                    float v = (float)acc[mt][nt][r] * sc;
                    pk |= ((unsigned)(q8i(v, qs) & 255)) << (8 * r);
                }
                *(unsigned*)(dst + ((size_t)b * 4096 + jj) * 2048 + sbase) = pk;
            }
        }
    } else if constexpr (EPI == 1) {
        const float sc = S_U * wsc;
        float* O = (float*)out0;
        #pragma unroll
        for (int mt = 0; mt < 4; mt++)
            #pragma unroll
            for (int r = 0; r < 4; r++) {
                const int m = m0w + mt * 16 + lk * 4 + r;
                #pragma unroll
                for (int nt = 0; nt < 4; nt++) {
                    const int j = n0w + nt * 16 + lr;
                    if (j < 160)
                        O[(size_t)m * 160 + j] = (float)acc[mt][nt][r] * sc;
                }
            }
    } else {
        const float sc = S_Y * wsc;
        float* O = (float*)out0;
        #pragma unroll
        for (int mt = 0; mt < 4; mt++)
            #pragma unroll
            for (int r = 0; r < 4; r++) {
                const int m = m0w + mt * 16 + lk * 4 + r;
                #pragma unroll
                for (int nt = 0; nt < 4; nt++)
                    O[(size_t)m * N + n0w + nt * 16 + lr] = (float)acc[mt][nt][r] * sc;
            }
    }
}

// ---------------- depthwise causal conv(K=4) + silu + quant ----------------
__global__ __launch_bounds__(256)
void k_conv(const i8* __restrict__ hsq, const i8* __restrict__ cwq,
            const float* __restrict__ conv_b, const unsigned* __restrict__ cmaxbits,
            i8* __restrict__ uq, i8* __restrict__ uqT) {
    __shared__ char lt[64][68];
    const int tid = threadIdx.x;
    const int b = blockIdx.z;
    const int d0 = blockIdx.y << 6;
    const int s0 = blockIdx.x << 6;
    const int dl = tid >> 2;
    const int sg = tid & 3;
    const int d = d0 + dl;
    const int sbase = s0 + (sg << 4);
    const i8* xp = hsq + ((size_t)b * 4096 + d) * 2048;
    int v[19];
    #pragma unroll
    for (int i = 0; i < 19; i++) {
        int s = sbase - 3 + i;
        v[i] = (s >= 0) ? (int)xp[s] : 0;
    }
    const unsigned cw = *(const unsigned*)(cwq + (size_t)d * 4);
    const int w0 = (int)(char)(cw & 255);
    const int w1 = (int)(char)((cw >> 8) & 255);
    const int w2 = (int)(char)((cw >> 16) & 255);
    const int w3 = (int)(char)((cw >> 24) & 255);
    const float cws = __uint_as_float(*cmaxbits) / 127.0f;
    const float sc = S_Z * cws;
    const float bias = conv_b[d];
    unsigned pk[4] = {0, 0, 0, 0};
    #pragma unroll
    for (int t = 0; t < 16; t++) {
        int acc = v[t] * w0 + v[t + 1] * w1 + v[t + 2] * w2 + v[t + 3] * w3;
        float f = __fadd_rn(__fmul_rn((float)acc, sc), bias);
        float sig = 1.0f / (1.0f + expf(-f));
        float sl = __fmul_rn(f, sig);
        int q = q8i(sl, S_U);
        pk[t >> 2] |= ((unsigned)(q & 255)) << ((t & 3) * 8);
        lt[(sg << 4) + t][dl] = (char)q;
    }
    *(int4*)(uq + ((size_t)b * 4096 + d) * 2048 + sbase) = make_int4(pk[0], pk[1], pk[2], pk[3]);
    __syncthreads();
    const int rr = tid >> 2;
    const int wg = tid & 3;
    const int* rp = (const int*)(&lt[rr][wg << 4]);
    int4 o; o.x = rp[0]; o.y = rp[1]; o.z = rp[2]; o.w = rp[3];
    *(int4*)(uqT + ((size_t)b * 2048 + s0 + rr) * 4096 + d0 + (wg << 4)) = o;
}

// ---------------- rmsnorm + quant; B/C written TRANSPOSED [b][n][s] ----------------
__global__ __launch_bounds__(64)
void k_rms(const float* __restrict__ p,
           const float* __restrict__ wdt, const float* __restrict__ wB, const float* __restrict__ wC,
           i8* __restrict__ dtq, i8* __restrict__ bqT, i8* __restrict__ cqT) {
    const int row = blockIdx.x;
    const int lane = threadIdx.x;
    const float* x = p + (size_t)row * 160;
    float a0 = x[lane], a1 = x[64 + lane];
    float bb = (lane < 16) ? x[128 + lane] : 0.0f;
    float cc = (lane < 16) ? x[144 + lane] : 0.0f;
    float sdt = __fadd_rn(__fmul_rn(a0, a0), __fmul_rn(a1, a1));
    float sB = __fmul_rn(bb, bb);
    float sC = __fmul_rn(cc, cc);
    #pragma unroll
    for (int off = 32; off; off >>= 1) {
        sdt = __fadd_rn(sdt, __shfl_xor(sdt, off));
        sB  = __fadd_rn(sB,  __shfl_xor(sB, off));
        sC  = __fadd_rn(sC,  __shfl_xor(sC, off));
    }
    float rdt = 1.0f / sqrtf(sdt / 128.0f + 1e-6f);
    float rB  = 1.0f / sqrtf(sB / 16.0f + 1e-6f);
    float rC  = 1.0f / sqrtf(sC / 16.0f + 1e-6f);
    dtq[(size_t)row * 128 + lane]      = (i8)q8i(__fmul_rn(wdt[lane],      __fmul_rn(a0, rdt)), S_DTLN);
    dtq[(size_t)row * 128 + 64 + lane] = (i8)q8i(__fmul_rn(wdt[64 + lane], __fmul_rn(a1, rdt)), S_DTLN);
    if (lane < 16) {
        size_t tpos = ((size_t)(row >> 11) * 16 + lane) * 2048 + (row & 2047);
        bqT[tpos] = (i8)q8i(__fmul_rn(wB[lane], __fmul_rn(bb, rB)), S_B);
        cqT[tpos] = (i8)q8i(__fmul_rn(wC[lane], __fmul_rn(cc, rC)), S_C);
    }
}

// ---------------- LUT builders (ubyte-indexed; entries bit-identical) ----------------
// entry at index q holds the value for signed byte ((q<128)? q : q-256)
__global__ __launch_bounds__(256)
void k_lut_dt(const float* __restrict__ dt_bias, float* __restrict__ lut) {
    const int d = blockIdx.x;
    const int q = threadIdx.x;
    const int sv = (q < 128) ? q : q - 256;
    const float bias = dt_bias[d];
    lut[(size_t)d * 256 + q] =
        softplus_f(__fadd_rn(__fmul_rn((float)sv, S_DT), bias));
}
__global__ __launch_bounds__(256)
void k_lut_silu(float* __restrict__ lut) {
    const int q = threadIdx.x;
    const int sv = (q < 128) ? q : q - 256;
    float gv = __fmul_rn((float)sv, S_Z);
    float sg = __fmul_rn(gv, 1.0f / (1.0f + expf(-gv)));
    lut[q] = sg;
}

// ---------------- scan v4: 16-step tiles + reduce-scatter tree (bit-exact) ----------------
__global__ __launch_bounds__(256)
void k_scan4(const i8* __restrict__ dt8, const i8* __restrict__ uq, const i8* __restrict__ gq,
             const i8* __restrict__ BqT, const i8* __restrict__ CqT,
             const float* __restrict__ lut_dt, const float* __restrict__ lut_silu,
             const float* __restrict__ A_log, const float* __restrict__ D_skip,
             i8* __restrict__ yq) {
    const int g = blockIdx.x * 256 + threadIdx.x;
    const int n = g & 15;
    const int bd = g >> 4;
    const int d = bd & 4095;
    const int b = bd >> 12;
    const float Acoef = -expf(A_log[(size_t)d * 16 + n]);
    const float Dd = D_skip[d];
    const float* ldt = lut_dt + (size_t)d * 256;
    const v4i* dtp = (const v4i*)(dt8 + (size_t)bd * 2048);
    const v4i* up  = (const v4i*)(uq  + (size_t)bd * 2048);
    const v4i* gp  = (const v4i*)(gq  + (size_t)bd * 2048);
    const v4i* Bp  = (const v4i*)(BqT + ((size_t)b * 16 + n) * 2048);
    const v4i* Cp  = (const v4i*)(CqT + ((size_t)b * 16 + n) * 2048);
    i8* yp = yq + (size_t)b * 2048 * 4096 + d;
    float h = 0.0f;
    v4i dtw = dtp[0], uw = up[0], gw = gp[0], bw = Bp[0], cw = Cp[0];
    for (int t = 0; t < 128; t++) {
        v4i ndt, nu, ng, nb, nc;
        if (t < 127) { ndt = dtp[t + 1]; nu = up[t + 1]; ng = gp[t + 1]; nb = Bp[t + 1]; nc = Cp[t + 1]; }
        float dtv[16], dA[16], pj[16], Cv[16], y[16];
        #pragma unroll
        for (int j = 0; j < 16; j++)
            dtv[j] = ldt[ubyte_of(dtw[j >> 2], j & 3)];
        #pragma unroll
        for (int j = 0; j < 16; j++)
            dA[j] = expf(__fmul_rn(dtv[j], Acoef));
        #pragma unroll
        for (int j = 0; j < 16; j++) {
            float uv = __fmul_rn((float)sbyte_of(uw[j >> 2], j & 3), S_U);
            float Bv = __fmul_rn((float)sbyte_of(bw[j >> 2], j & 3), S_B);
            Cv[j] = __fmul_rn((float)sbyte_of(cw[j >> 2], j & 3), S_C);
            pj[j] = __fmul_rn(__fmul_rn(dtv[j], uv), Bv);
        }
        #pragma unroll
        for (int j = 0; j < 16; j++) {
            h = __fadd_rn(__fmul_rn(h, dA[j]), pj[j]);
            y[j] = __fmul_rn(h, Cv[j]);
        }
        // reduce-scatter: same pairwise tree as the xor-1/2/4/8 butterfly (bit-exact)
        float w8[8];
        #pragma unroll
        for (int i = 0; i < 8; i++) {
            float a = y[2 * i], bq = y[2 * i + 1];
            float snd = (n & 1) ? a : bq;
            float rcv = __shfl_xor(snd, 1);
            float kept = (n & 1) ? bq : a;
            w8[i] = __fadd_rn(kept, rcv);
        }
        float w4[4];
        #pragma unroll
        for (int i = 0; i < 4; i++) {
            float a = w8[2 * i], bq = w8[2 * i + 1];
            float snd = (n & 2) ? a : bq;
            float rcv = __shfl_xor(snd, 2);
            float kept = (n & 2) ? bq : a;
            w4[i] = __fadd_rn(kept, rcv);
        }
        float w2[2];
        #pragma unroll
        for (int i = 0; i < 2; i++) {
            float a = w4[2 * i], bq = w4[2 * i + 1];
            float snd = (n & 4) ? a : bq;
            float rcv = __shfl_xor(snd, 4);
            float kept = (n & 4) ? bq : a;
            w2[i] = __fadd_rn(kept, rcv);
        }
        float ysave;
        {
            float a = w2[0], bq = w2[1];
            float snd = (n & 8) ? a : bq;
            float rcv = __shfl_xor(snd, 8);
            float kept = (n & 8) ? bq : a;
            ysave = __fadd_rn(kept, rcv);
        }
        // epilogue: lane n handles s = t*16 + n
        int uws = (n & 8) ? ((n & 4) ? uw[3] : uw[2]) : ((n & 4) ? uw[1] : uw[0]);
        int gws = (n & 8) ? ((n & 4) ? gw[3] : gw[2]) : ((n & 4) ? gw[1] : gw[0]);
        float uvn = __fmul_rn((float)(int)(signed char)((unsigned)uws >> ((n & 3) * 8)), S_U);
        int gb = (int)(((unsigned)gws >> ((n & 3) * 8)) & 255u);
        float ys = __fadd_rn(ysave, __fmul_rn(uvn, Dd));
        float sg = lut_silu[gb];
        float vv = __fmul_rn(ys, sg);
        yp[(size_t)(t * 16 + n) * 4096] = (i8)q8i(vv, S_Y);
        if (t < 127) { dtw = ndt; uw = nu; gw = ng; bw = nb; cw = nc; }
    }
}

extern "C" void kernel_launch(void* const* d_in, const int* in_sizes, int n_in,
                              void* d_out, int out_size, void* d_ws, size_t ws_size,
                              hipStream_t stream) {
    const float* hidden   = (const float*)d_in[0];
    const float* in_proj  = (const float*)d_in[1];
    const float* conv_w   = (const float*)d_in[2];
    const float* conv_b   = (const float*)d_in[3];
    const float* x_proj   = (const float*)d_in[4];
    const float* dt_ln    = (const float*)d_in[5];
    const float* B_ln     = (const float*)d_in[6];
    const float* C_ln     = (const float*)d_in[7];
    const float* dt_proj  = (const float*)d_in[8];
    const float* dt_bias  = (const float*)d_in[9];
    const float* A_log    = (const float*)d_in[10];
    const float* D_skip   = (const float*)d_in[11];
    const float* out_proj = (const float*)d_in[12];
    float* out = (float*)d_out;

    // ---- workspace layout, 46,810,368 B high-water ----
    char* ws = (char*)d_ws;
    unsigned* scales = (unsigned*)ws;                       // 256 B
    i8* WQ   = (i8*)(ws + 256);                             // 16,777,216: in_proj q8 -> u_qT -> y_q
    i8* XQ   = (i8*)(ws + 16777472);                        //  8,388,608: x_q -> OWQ
    i8* HSQ  = (i8*)(ws + 25166080);                        // 16,777,216: hs_q -> dt8
    char* S0 = ws + 41943296;
    float* SSMP = (float*)S0;                               // 2,621,440: ssm_p [4096][160]
    i8* XWQp = (i8*)(S0 + 2621440);                         // 1,048,576: x_proj q8 padded [256][4096]
    i8* DTQb = (i8*)(S0 + 3670016);                         //   524,288: dt_q [4096][128]
    i8* DWQ  = (i8*)(S0 + 4194304);                         //   524,288: dt_proj q8
    i8* CWQ  = (i8*)(S0 + 4718592);                         //    16,384: conv q8
    float* LUTSI = (float*)(S0 + 4734976);                  //     1,024
    i8* BQT  = (i8*)(S0 + 4736000);                         //    65,536: B_q^T [2][16][2048]
    i8* CQT  = (i8*)(S0 + 4801536);                         //    65,536: C_q^T
    // LUTDT (4 MB) overlays SSMP+XWQp+DTQb-head; all three dead once it is built
    float* LUTDT = (float*)S0;

    i8* GQ = (i8*)d_out;                                    // gate_q [2][4096][2048]
    i8* UQ = (i8*)d_out + 16777216;                         // u_q    [2][4096][2048]
    i8* UQT = WQ;                                           // u_qT [2][2048][4096]
    i8* OWQ = XQ;                                           // out_proj q8
    i8* DT8 = HSQ;                                          // dt8 [2][4096][2048]
    i8* YQ  = WQ;                                           // y_q [2][2048][4096]

    hipMemsetAsync(scales, 0, 256, stream);
    hipMemsetAsync(XWQp, 0, 1048576, stream);               // zero pad rows 160..255

    k_maxabs<<<2048, 256, 0, stream>>>(in_proj, 16777216LL, scales + 0);
    k_maxabs<<<64,   256, 0, stream>>>(conv_w,  16384LL,    scales + 1);
    k_maxabs<<<512,  256, 0, stream>>>(x_proj,  655360LL,   scales + 2);
    k_maxabs<<<512,  256, 0, stream>>>(dt_proj, 524288LL,   scales + 3);
    k_maxabs<<<1024, 256, 0, stream>>>(out_proj, 8388608LL, scales + 4);

    k_quant_w<<<16384, 256, 0, stream>>>(in_proj, 16777216LL, scales + 0, WQ);
    k_quant_w<<<16,    256, 0, stream>>>(conv_w,  16384LL,    scales + 1, CWQ);
    k_quant_w<<<640,   256, 0, stream>>>(x_proj,  655360LL,   scales + 2, XWQp);
    k_quant_w<<<512,   256, 0, stream>>>(dt_proj, 524288LL,   scales + 3, DWQ);
    k_quant_x<<<8192,  256, 0, stream>>>(hidden,  8388608LL,  S_IN, XQ);

    // GEMM1 (MFMA): proj -> hs_q(HSQ) / gate_q(GQ), int8 [b,d,s]
    k_mgemm<0><<<dim3(64, 32), 256, 0, stream>>>(XQ, WQ, 4096, 8192, 2048, scales + 0, HSQ, GQ);

    k_quant_w<<<8192, 256, 0, stream>>>(out_proj, 8388608LL, scales + 4, OWQ);

    dim3 gc(32, 64, 2);
    k_conv<<<gc, 256, 0, stream>>>(HSQ, CWQ, conv_b, scales + 1, UQ, UQT);

    // GEMM2 (MFMA, zero-padded B to 256 rows, stores guarded to j<160): ssm_p
    k_mgemm<1><<<dim3(2, 32), 256, 0, stream>>>(UQT, XWQp, 4096, 256, 4096, scales + 2, SSMP, nullptr);

    k_rms<<<4096, 64, 0, stream>>>(SSMP, dt_ln, B_ln, C_ln, DTQb, BQT, CQT);

    // GEMM3 (MFMA): dt8 -> [b,d,s] into HSQ
    k_mgemm<2><<<dim3(32, 32), 256, 0, stream>>>(DTQb, DWQ, 4096, 4096, 128, scales + 3, DT8, nullptr);

    k_lut_dt<<<4096, 256, 0, stream>>>(dt_bias, LUTDT);
    k_lut_silu<<<1, 256, 0, stream>>>(LUTSI);

    k_scan4<<<512, 256, 0, stream>>>(DT8, UQ, GQ, BQT, CQT, LUTDT, LUTSI, A_log, D_skip, YQ);

    // GEMM4 (MFMA): out = y_q @ out_proj^T -> f32
    k_mgemm<3><<<dim3(16, 32), 256, 0, stream>>>(YQ, OWQ, 4096, 2048, 4096, scales + 4, out, nullptr);
}

// Round 11
// 658.350 us; speedup vs baseline: 4.7679x; 1.0663x over previous
//
#include <hip/hip_runtime.h>
#include <stdint.h>

typedef signed char i8;
typedef int v4i __attribute__((ext_vector_type(4)));

#define S_IN  0.05f
#define S_Z   0.02f
#define S_U   0.01f
#define S_DTLN 0.02f
#define S_B   0.02f
#define S_C   0.02f
#define S_DT  0.01f
#define S_Y   0.01f

// qa(): round-half-even (matches jnp.round), clip to [-128,127]
__device__ __forceinline__ float q8f(float x, float s) {
    float r = rintf(x / s);
    return fmaxf(-128.0f, fminf(127.0f, r));
}
__device__ __forceinline__ int q8i(float x, float s) { return (int)q8f(x, s); }

__device__ __forceinline__ float softplus_f(float x) {
    return __fadd_rn(fmaxf(x, 0.0f), log1pf(expf(-fabsf(x))));
}

__device__ __forceinline__ int sbyte_of(int w, int j) {
    return (int)(signed char)((unsigned)w >> (j * 8));
}
__device__ __forceinline__ int ubyte_of(int w, int j) {
    return (int)(((unsigned)w >> (j * 8)) & 255u);
}

// async global->LDS, 16B per lane; LDS dest = wave-uniform base + lane*16
__device__ __forceinline__ void gload16(const i8* g, i8* lds) {
    __builtin_amdgcn_global_load_lds(
        (const __attribute__((address_space(1))) unsigned int*)g,
        (__attribute__((address_space(3))) unsigned int*)lds,
        16, 0, 0);
}

// ---------------- fused max|w| over the 5 weight tensors ----------------
// blocks: [0,2048) in_proj | [2048,2112) conv | [2112,2624) x_proj |
//         [2624,3136) dt_proj | [3136,4160) out_proj
__global__ __launch_bounds__(256)
void k_maxabs_all(const float* __restrict__ a0, const float* __restrict__ a1,
                  const float* __restrict__ a2, const float* __restrict__ a3,
                  const float* __restrict__ a4, unsigned* __restrict__ out) {
    int bid = blockIdx.x;
    const float* w; long long n; int slot, nb;
    if (bid < 2048)      { w = a0; n = 16777216LL; slot = 0; nb = 2048; }
    else if (bid < 2112) { w = a1; n = 16384LL;    slot = 1; nb = 64;   bid -= 2048; }
    else if (bid < 2624) { w = a2; n = 655360LL;   slot = 2; nb = 512;  bid -= 2112; }
    else if (bid < 3136) { w = a3; n = 524288LL;   slot = 3; nb = 512;  bid -= 2624; }
    else                 { w = a4; n = 8388608LL;  slot = 4; nb = 1024; bid -= 3136; }
    unsigned m = 0;
    long long stride = (long long)nb * 256;
    for (long long i = (long long)bid * 256 + threadIdx.x; i < n; i += stride)
        m = max(m, __float_as_uint(fabsf(w[i])));
    #pragma unroll
    for (int off = 32; off; off >>= 1) {
        unsigned o = (unsigned)__shfl_xor((int)m, off);
        m = max(m, o);
    }
    __shared__ unsigned sm[4];
    if ((threadIdx.x & 63) == 0) sm[threadIdx.x >> 6] = m;
    __syncthreads();
    if (threadIdx.x == 0) {
        unsigned r = max(max(sm[0], sm[1]), max(sm[2], sm[3]));
        atomicMax(out + slot, r);
    }
}

// ---------------- fused quant: 4 weights + hidden activation ----------------
// blocks: [0,16384) in_proj | [16384,16400) conv | [16400,17040) x_proj |
//         [17040,17552) dt_proj | [17552,25744) hidden (fixed S_IN)
__global__ __launch_bounds__(256)
void k_quant_all(const float* __restrict__ a0, const float* __restrict__ a1,
                 const float* __restrict__ a2, const float* __restrict__ a3,
                 const float* __restrict__ ax, const unsigned* __restrict__ scales,
                 i8* __restrict__ o0, i8* __restrict__ o1, i8* __restrict__ o2,
                 i8* __restrict__ o3, i8* __restrict__ ox) {
    int bid = blockIdx.x;
    const float* w; i8* o; float s;
    if (bid < 16384)      { w = a0; o = o0; s = __uint_as_float(scales[0]) / 127.0f; }
    else if (bid < 16400) { w = a1; o = o1; s = __uint_as_float(scales[1]) / 127.0f; bid -= 16384; }
    else if (bid < 17040) { w = a2; o = o2; s = __uint_as_float(scales[2]) / 127.0f; bid -= 16400; }
    else if (bid < 17552) { w = a3; o = o3; s = __uint_as_float(scales[3]) / 127.0f; bid -= 17040; }
    else                  { w = ax; o = ox; s = S_IN;                                 bid -= 17552; }
    long long i = ((long long)bid * 256 + threadIdx.x) * 4;
    float4 v = *(const float4*)(w + i);
    unsigned pk = ((unsigned)(q8i(v.x, s) & 255))
                | ((unsigned)(q8i(v.y, s) & 255) << 8)
                | ((unsigned)(q8i(v.z, s) & 255) << 16)
                | ((unsigned)(q8i(v.w, s) & 255) << 24);
    *(unsigned*)(o + i) = pk;
}

// ---------------- single weight quant (out_proj, runs after GEMM1) ----------------
__global__ __launch_bounds__(256)
void k_quant_w(const float* __restrict__ w, long long n,
               const unsigned* __restrict__ maxbits, i8* __restrict__ o) {
    long long i = ((long long)blockIdx.x * 256 + threadIdx.x) * 4;
    if (i >= n) return;
    float s = __uint_as_float(*maxbits) / 127.0f;
    float4 v = *(const float4*)(w + i);
    unsigned pk = ((unsigned)(q8i(v.x, s) & 255))
                | ((unsigned)(q8i(v.y, s) & 255) << 8)
                | ((unsigned)(q8i(v.z, s) & 255) << 16)
                | ((unsigned)(q8i(v.w, s) & 255) << 24);
    *(unsigned*)(o + i) = pk;
}

// ---------------- MFMA int8 GEMM: LDS-staged, 128x128 tile, BK=128 bytes ----------------
// LDS per operand: 8 subtiles x 16 rows x 128B = 16KB; byte = st*2048 + kc*256 + r*16.
// K = row stride AND total K; per-block K-range = K/gridDim.z (split-K via blockIdx.z).
// EPI 0: int8 transposed split hs/gate; EPI 1: int32 atomicAdd partials into [m][160];
// EPI 2: int8 transposed dt8; EPI 3: f32 out.
template<int EPI>
__global__ __launch_bounds__(256)
void k_mgemm(const i8* __restrict__ A, const i8* __restrict__ Bw,
             int M, int N, int K,
             const unsigned* __restrict__ wmaxbits,
             void* __restrict__ out0, void* __restrict__ out1) {
    __shared__ i8 sA[16384];
    __shared__ i8 sB[16384];
    const int tid = threadIdx.x;
    const int w = tid >> 6;
    const int l = tid & 63;
    // bijective XCD swizzle over linearized xy-grid (nwg % 8 == 0 for all our grids)
    int id = blockIdx.y * gridDim.x + blockIdx.x;
    const int qq = (gridDim.x * gridDim.y) >> 3;
    id = (id & 7) * qq + (id >> 3);
    const int m0 = (id / gridDim.x) << 7;
    const int n0 = (id % gridDim.x) << 7;
    const int kLen = K / gridDim.z;
    const int kOff = blockIdx.z * kLen;
    const int lr = l & 15;
    const int lk = l >> 4;
    const i8* gA = A  + (size_t)(m0 + lr) * K + lk * 16;
    const i8* gB = Bw + (size_t)(n0 + lr) * K + lk * 16;
    const size_t rowK16 = (size_t)16 * K;
    const int mw = (w >> 1) * 4;
    const int nw = (w & 1) * 4;
    const int rdoff = lk * 256 + lr * 16;
    v4i acc[4][4] = {};
    for (int k0 = kOff; k0 < kOff + kLen; k0 += 128) {
        gload16(gA + rowK16 * w + k0,            sA + w * 2048);
        gload16(gA + rowK16 * w + k0 + 64,       sA + w * 2048 + 1024);
        gload16(gA + rowK16 * (4 + w) + k0,      sA + (4 + w) * 2048);
        gload16(gA + rowK16 * (4 + w) + k0 + 64, sA + (4 + w) * 2048 + 1024);
        gload16(gB + rowK16 * w + k0,            sB + w * 2048);
        gload16(gB + rowK16 * w + k0 + 64,       sB + w * 2048 + 1024);
        gload16(gB + rowK16 * (4 + w) + k0,      sB + (4 + w) * 2048);
        gload16(gB + rowK16 * (4 + w) + k0 + 64, sB + (4 + w) * 2048 + 1024);
        __syncthreads();
        #pragma unroll
        for (int k64 = 0; k64 < 2; k64++) {
            v4i af[4], bf[4];
            #pragma unroll
            for (int t = 0; t < 4; t++) {
                af[t] = *(const v4i*)(sA + (mw + t) * 2048 + k64 * 1024 + rdoff);
                bf[t] = *(const v4i*)(sB + (nw + t) * 2048 + k64 * 1024 + rdoff);
            }
            #pragma unroll
            for (int mt = 0; mt < 4; mt++)
                #pragma unroll
                for (int nt = 0; nt < 4; nt++)
                    acc[mt][nt] = __builtin_amdgcn_mfma_i32_16x16x64_i8(af[mt], bf[nt], acc[mt][nt], 0, 0, 0);
        }
        __syncthreads();
    }
    const float wsc = __uint_as_float(*wmaxbits) / 127.0f;
    const int m0w = m0 + (w >> 1) * 64;
    const int n0w = n0 + (w & 1) * 64;
    if constexpr (EPI == 0 || EPI == 2) {
        const float sc = (EPI == 0 ? S_IN : S_DTLN) * wsc;
        const float qs = (EPI == 0 ? S_Z : S_DT);
        const int b = m0w >> 11;
        #pragma unroll
        for (int nt = 0; nt < 4; nt++) {
            const int j = n0w + nt * 16 + lr;
            i8* dst;
            if constexpr (EPI == 0) dst = (j < 4096) ? (i8*)out0 : (i8*)out1;
            else dst = (i8*)out0;
            const int jj = j & 4095;
            #pragma unroll
            for (int mt = 0; mt < 4; mt++) {
                const int sbase = (m0w & 2047) + mt * 16 + lk * 4;
                unsigned pk = 0;
                #pragma unroll
                for (int r = 0; r < 4; r++) {
                    float v = (float)acc[mt][nt][r] * sc;
                    pk |= ((unsigned)(q8i(v, qs) & 255)) << (8 * r);
                }
                *(unsigned*)(dst + ((size_t)b * 4096 + jj) * 2048 + sbase) = pk;
            }
        }
    } else if constexpr (EPI == 1) {
        // split-K partials: exact int32 accumulation, order-independent
        int* O = (int*)out0;
        #pragma unroll
        for (int mt = 0; mt < 4; mt++)
            #pragma unroll
            for (int r = 0; r < 4; r++) {
                const int m = m0w + mt * 16 + lk * 4 + r;
                #pragma unroll
                for (int nt = 0; nt < 4; nt++) {
                    const int j = n0w + nt * 16 + lr;
                    if (j < 160)
                        atomicAdd(O + (size_t)m * 160 + j, acc[mt][nt][r]);
                }
            }
    } else {
        const float sc = S_Y * wsc;
        float* O = (float*)out0;
        #pragma unroll
        for (int mt = 0; mt < 4; mt++)
            #pragma unroll
            for (int r = 0; r < 4; r++) {
                const int m = m0w + mt * 16 + lk * 4 + r;
                #pragma unroll
                for (int nt = 0; nt < 4; nt++)
                    O[(size_t)m * N + n0w + nt * 16 + lr] = (float)acc[mt][nt][r] * sc;
            }
    }
}

// ---------------- depthwise causal conv(K=4) + silu + quant ----------------
__global__ __launch_bounds__(256)
void k_conv(const i8* __restrict__ hsq, const i8* __restrict__ cwq,
            const float* __restrict__ conv_b, const unsigned* __restrict__ cmaxbits,
            i8* __restrict__ uq, i8* __restrict__ uqT) {
    __shared__ char lt[64][68];
    const int tid = threadIdx.x;
    const int b = blockIdx.z;
    const int d0 = blockIdx.y << 6;
    const int s0 = blockIdx.x << 6;
    const int dl = tid >> 2;
    const int sg = tid & 3;
    const int d = d0 + dl;
    const int sbase = s0 + (sg << 4);
    const i8* xp = hsq + ((size_t)b * 4096 + d) * 2048;
    int v[19];
    #pragma unroll
    for (int i = 0; i < 19; i++) {
        int s = sbase - 3 + i;
        v[i] = (s >= 0) ? (int)xp[s] : 0;
    }
    const unsigned cw = *(const unsigned*)(cwq + (size_t)d * 4);
    const int w0 = (int)(char)(cw & 255);
    const int w1 = (int)(char)((cw >> 8) & 255);
    const int w2 = (int)(char)((cw >> 16) & 255);
    const int w3 = (int)(char)((cw >> 24) & 255);
    const float cws = __uint_as_float(*cmaxbits) / 127.0f;
    const float sc = S_Z * cws;
    const float bias = conv_b[d];
    unsigned pk[4] = {0, 0, 0, 0};
    #pragma unroll
    for (int t = 0; t < 16; t++) {
        int acc = v[t] * w0 + v[t + 1] * w1 + v[t + 2] * w2 + v[t + 3] * w3;
        float f = __fadd_rn(__fmul_rn((float)acc, sc), bias);
        float sig = 1.0f / (1.0f + expf(-f));
        float sl = __fmul_rn(f, sig);
        int q = q8i(sl, S_U);
        pk[t >> 2] |= ((unsigned)(q & 255)) << ((t & 3) * 8);
        lt[(sg << 4) + t][dl] = (char)q;
    }
    *(int4*)(uq + ((size_t)b * 4096 + d) * 2048 + sbase) = make_int4(pk[0], pk[1], pk[2], pk[3]);
    __syncthreads();
    const int rr = tid >> 2;
    const int wg = tid & 3;
    const int* rp = (const int*)(&lt[rr][wg << 4]);
    int4 o; o.x = rp[0]; o.y = rp[1]; o.z = rp[2]; o.w = rp[3];
    *(int4*)(uqT + ((size_t)b * 2048 + s0 + rr) * 4096 + d0 + (wg << 4)) = o;
}

// ---------------- rmsnorm + quant; input is int32 partial sums; B/C transposed ----------------
__global__ __launch_bounds__(64)
void k_rms(const int* __restrict__ p, const unsigned* __restrict__ xsc,
           const float* __restrict__ wdt, const float* __restrict__ wB, const float* __restrict__ wC,
           i8* __restrict__ dtq, i8* __restrict__ bqT, i8* __restrict__ cqT) {
    const int row = blockIdx.x;
    const int lane = threadIdx.x;
    // dequant identical to old GEMM2 epilogue: (float)acc * (S_U * wsc), single mul
    const float scp = S_U * (__uint_as_float(*xsc) / 127.0f);
    const int* x = p + (size_t)row * 160;
    float a0 = (float)x[lane] * scp;
    float a1 = (float)x[64 + lane] * scp;
    float bb = (lane < 16) ? (float)x[128 + lane] * scp : 0.0f;
    float cc = (lane < 16) ? (float)x[144 + lane] * scp : 0.0f;
    float sdt = __fadd_rn(__fmul_rn(a0, a0), __fmul_rn(a1, a1));
    float sB = __fmul_rn(bb, bb);
    float sC = __fmul_rn(cc, cc);
    #pragma unroll
    for (int off = 32; off; off >>= 1) {
        sdt = __fadd_rn(sdt, __shfl_xor(sdt, off));
        sB  = __fadd_rn(sB,  __shfl_xor(sB, off));
        sC  = __fadd_rn(sC,  __shfl_xor(sC, off));
    }
    float rdt = 1.0f / sqrtf(sdt / 128.0f + 1e-6f);
    float rB  = 1.0f / sqrtf(sB / 16.0f + 1e-6f);
    float rC  = 1.0f / sqrtf(sC / 16.0f + 1e-6f);
    dtq[(size_t)row * 128 + lane]      = (i8)q8i(__fmul_rn(wdt[lane],      __fmul_rn(a0, rdt)), S_DTLN);
    dtq[(size_t)row * 128 + 64 + lane] = (i8)q8i(__fmul_rn(wdt[64 + lane], __fmul_rn(a1, rdt)), S_DTLN);
    if (lane < 16) {
        size_t tpos = ((size_t)(row >> 11) * 16 + lane) * 2048 + (row & 2047);
        bqT[tpos] = (i8)q8i(__fmul_rn(wB[lane], __fmul_rn(bb, rB)), S_B);
        cqT[tpos] = (i8)q8i(__fmul_rn(wC[lane], __fmul_rn(cc, rC)), S_C);
    }
}

// ---------------- fused LUT builder: blocks 0..4095 dt rows, block 4096 silu ----------------
__global__ __launch_bounds__(256)
void k_lut_all(const float* __restrict__ dt_bias, float* __restrict__ lutdt,
               float* __restrict__ lutsi) {
    const int q = threadIdx.x;
    const int sv = (q < 128) ? q : q - 256;
    if (blockIdx.x < 4096) {
        const int d = blockIdx.x;
        const float bias = dt_bias[d];
        lutdt[(size_t)d * 256 + q] =
            softplus_f(__fadd_rn(__fmul_rn((float)sv, S_DT), bias));
    } else {
        float gv = __fmul_rn((float)sv, S_Z);
        float sg = __fmul_rn(gv, 1.0f / (1.0f + expf(-gv)));
        lutsi[q] = sg;
    }
}

// ---------------- scan v4: 16-step tiles + reduce-scatter tree (bit-exact) ----------------
__global__ __launch_bounds__(256)
void k_scan4(const i8* __restrict__ dt8, const i8* __restrict__ uq, const i8* __restrict__ gq,
             const i8* __restrict__ BqT, const i8* __restrict__ CqT,
             const float* __restrict__ lut_dt, const float* __restrict__ lut_silu,
             const float* __restrict__ A_log, const float* __restrict__ D_skip,
             i8* __restrict__ yq) {
    const int g = blockIdx.x * 256 + threadIdx.x;
    const int n = g & 15;
    const int bd = g >> 4;
    const int d = bd & 4095;
    const int b = bd >> 12;
    const float Acoef = -expf(A_log[(size_t)d * 16 + n]);
    const float Dd = D_skip[d];
    const float* ldt = lut_dt + (size_t)d * 256;
    const v4i* dtp = (const v4i*)(dt8 + (size_t)bd * 2048);
    const v4i* up  = (const v4i*)(uq  + (size_t)bd * 2048);
    const v4i* gp  = (const v4i*)(gq  + (size_t)bd * 2048);
    const v4i* Bp  = (const v4i*)(BqT + ((size_t)b * 16 + n) * 2048);
    const v4i* Cp  = (const v4i*)(CqT + ((size_t)b * 16 + n) * 2048);
    i8* yp = yq + (size_t)b * 2048 * 4096 + d;
    float h = 0.0f;
    v4i dtw = dtp[0], uw = up[0], gw = gp[0], bw = Bp[0], cw = Cp[0];
    for (int t = 0; t < 128; t++) {
        v4i ndt, nu, ng, nb, nc;
        if (t < 127) { ndt = dtp[t + 1]; nu = up[t + 1]; ng = gp[t + 1]; nb = Bp[t + 1]; nc = Cp[t + 1]; }
        float dtv[16], dA[16], pj[16], Cv[16], y[16];
        #pragma unroll
        for (int j = 0; j < 16; j++)
            dtv[j] = ldt[ubyte_of(dtw[j >> 2], j & 3)];
        #pragma unroll
        for (int j = 0; j < 16; j++)
            dA[j] = expf(__fmul_rn(dtv[j], Acoef));
        #pragma unroll
        for (int j = 0; j < 16; j++) {
            float uv = __fmul_rn((float)sbyte_of(uw[j >> 2], j & 3), S_U);
            float Bv = __fmul_rn((float)sbyte_of(bw[j >> 2], j & 3), S_B);
            Cv[j] = __fmul_rn((float)sbyte_of(cw[j >> 2], j & 3), S_C);
            pj[j] = __fmul_rn(__fmul_rn(dtv[j], uv), Bv);
        }
        #pragma unroll
        for (int j = 0; j < 16; j++) {
            h = __fadd_rn(__fmul_rn(h, dA[j]), pj[j]);
            y[j] = __fmul_rn(h, Cv[j]);
        }
        // reduce-scatter: same pairwise tree as the xor-1/2/4/8 butterfly (bit-exact)
        float w8[8];
        #pragma unroll
        for (int i = 0; i < 8; i++) {
            float a = y[2 * i], bq = y[2 * i + 1];
            float snd = (n & 1) ? a : bq;
            float rcv = __shfl_xor(snd, 1);
            float kept = (n & 1) ? bq : a;
            w8[i] = __fadd_rn(kept, rcv);
        }
        float w4[4];
        #pragma unroll
        for (int i = 0; i < 4; i++) {
            float a = w8[2 * i], bq = w8[2 * i + 1];
            float snd = (n & 2) ? a : bq;
            float rcv = __shfl_xor(snd, 2);
            float kept = (n & 2) ? bq : a;
            w4[i] = __fadd_rn(kept, rcv);
        }
        float w2[2];
        #pragma unroll
        for (int i = 0; i < 2; i++) {
            float a = w4[2 * i], bq = w4[2 * i + 1];
            float snd = (n & 4) ? a : bq;
            float rcv = __shfl_xor(snd, 4);
            float kept = (n & 4) ? bq : a;
            w2[i] = __fadd_rn(kept, rcv);
        }
        float ysave;
        {
            float a = w2[0], bq = w2[1];
            float snd = (n & 8) ? a : bq;
            float rcv = __shfl_xor(snd, 8);
            float kept = (n & 8) ? bq : a;
            ysave = __fadd_rn(kept, rcv);
        }
        // epilogue: lane n handles s = t*16 + n
        int uws = (n & 8) ? ((n & 4) ? uw[3] : uw[2]) : ((n & 4) ? uw[1] : uw[0]);
        int gws = (n & 8) ? ((n & 4) ? gw[3] : gw[2]) : ((n & 4) ? gw[1] : gw[0]);
        float uvn = __fmul_rn((float)(int)(signed char)((unsigned)uws >> ((n & 3) * 8)), S_U);
        int gb = (int)(((unsigned)gws >> ((n & 3) * 8)) & 255u);
        float ys = __fadd_rn(ysave, __fmul_rn(uvn, Dd));
        float sg = lut_silu[gb];
        float vv = __fmul_rn(ys, sg);
        yp[(size_t)(t * 16 + n) * 4096] = (i8)q8i(vv, S_Y);
        if (t < 127) { dtw = ndt; uw = nu; gw = ng; bw = nb; cw = nc; }
    }
}

extern "C" void kernel_launch(void* const* d_in, const int* in_sizes, int n_in,
                              void* d_out, int out_size, void* d_ws, size_t ws_size,
                              hipStream_t stream) {
    const float* hidden   = (const float*)d_in[0];
    const float* in_proj  = (const float*)d_in[1];
    const float* conv_w   = (const float*)d_in[2];
    const float* conv_b   = (const float*)d_in[3];
    const float* x_proj   = (const float*)d_in[4];
    const float* dt_ln    = (const float*)d_in[5];
    const float* B_ln     = (const float*)d_in[6];
    const float* C_ln     = (const float*)d_in[7];
    const float* dt_proj  = (const float*)d_in[8];
    const float* dt_bias  = (const float*)d_in[9];
    const float* A_log    = (const float*)d_in[10];
    const float* D_skip   = (const float*)d_in[11];
    const float* out_proj = (const float*)d_in[12];
    float* out = (float*)d_out;

    // ---- workspace layout, 46,810,368 B high-water ----
    char* ws = (char*)d_ws;
    unsigned* scales = (unsigned*)ws;                       // 256 B
    i8* WQ   = (i8*)(ws + 256);                             // 16,777,216: in_proj q8 -> u_qT -> y_q
    i8* XQ   = (i8*)(ws + 16777472);                        //  8,388,608: x_q -> OWQ
    i8* HSQ  = (i8*)(ws + 25166080);                        // 16,777,216: hs_q -> dt8
    char* S0 = ws + 41943296;
    int*  SSMP = (int*)S0;                                  // 2,621,440: ssm_p int32 [4096][160]
    i8* XWQp = (i8*)(S0 + 2621440);                         // 1,048,576: x_proj q8 padded [256][4096]
    i8* DTQb = (i8*)(S0 + 3670016);                         //   524,288: dt_q [4096][128]
    i8* DWQ  = (i8*)(S0 + 4194304);                         //   524,288: dt_proj q8
    i8* CWQ  = (i8*)(S0 + 4718592);                         //    16,384: conv q8
    float* LUTSI = (float*)(S0 + 4734976);                  //     1,024
    i8* BQT  = (i8*)(S0 + 4736000);                         //    65,536: B_q^T [2][16][2048]
    i8* CQT  = (i8*)(S0 + 4801536);                         //    65,536: C_q^T
    // LUTDT (4 MB) overlays SSMP+XWQp+DTQb-head; all three dead once it is built
    float* LUTDT = (float*)S0;

    i8* GQ = (i8*)d_out;                                    // gate_q [2][4096][2048]
    i8* UQ = (i8*)d_out + 16777216;                         // u_q    [2][4096][2048]
    i8* UQT = WQ;                                           // u_qT [2][2048][4096]
    i8* OWQ = XQ;                                           // out_proj q8
    i8* DT8 = HSQ;                                          // dt8 [2][4096][2048]
    i8* YQ  = WQ;                                           // y_q [2][2048][4096]

    hipMemsetAsync(scales, 0, 256, stream);
    hipMemsetAsync(SSMP, 0, 2621440, stream);               // split-K accumulator
    hipMemsetAsync(XWQp, 0, 1048576, stream);               // zero pad rows 160..255

    // fused absmax over all 5 weight tensors
    k_maxabs_all<<<4160, 256, 0, stream>>>(in_proj, conv_w, x_proj, dt_proj, out_proj, scales);

    // fused quant: in_proj/conv/x_proj/dt_proj weights + hidden activation
    k_quant_all<<<25744, 256, 0, stream>>>(in_proj, conv_w, x_proj, dt_proj, hidden,
                                           scales, WQ, CWQ, XWQp, DWQ, XQ);

    // GEMM1 (MFMA): proj -> hs_q(HSQ) / gate_q(GQ), int8 [b,d,s]
    k_mgemm<0><<<dim3(64, 32), 256, 0, stream>>>(XQ, WQ, 4096, 8192, 2048, scales + 0, HSQ, GQ);

    k_quant_w<<<8192, 256, 0, stream>>>(out_proj, 8388608LL, scales + 4, OWQ);

    dim3 gc(32, 64, 2);
    k_conv<<<gc, 256, 0, stream>>>(HSQ, CWQ, conv_b, scales + 1, UQ, UQT);

    // GEMM2 (MFMA, split-K=8, int32 atomic partials into SSMP)
    k_mgemm<1><<<dim3(2, 32, 8), 256, 0, stream>>>(UQT, XWQp, 4096, 256, 4096, scales + 2, SSMP, nullptr);

    k_rms<<<4096, 64, 0, stream>>>(SSMP, scales + 2, dt_ln, B_ln, C_ln, DTQb, BQT, CQT);

    // GEMM3 (MFMA): dt8 -> [b,d,s] into HSQ
    k_mgemm<2><<<dim3(32, 32), 256, 0, stream>>>(DTQb, DWQ, 4096, 4096, 128, scales + 3, DT8, nullptr);

    // fused LUT builders (SSMP/XWQp/DTQb dead now)
    k_lut_all<<<4097, 256, 0, stream>>>(dt_bias, LUTDT, LUTSI);

    k_scan4<<<512, 256, 0, stream>>>(DT8, UQ, GQ, BQT, CQT, LUTDT, LUTSI, A_log, D_skip, YQ);

    // GEMM4 (MFMA): out = y_q @ out_proj^T -> f32
    k_mgemm<3><<<dim3(16, 32), 256, 0, stream>>>(YQ, OWQ, 4096, 2048, 4096, scales + 4, out, nullptr);
}